// Round 7
// baseline (3041.983 us; speedup 1.0000x reference)
//
#include <hip/hip_runtime.h>
#include <cfloat>
#include <cstdint>

// Problem constants
constexpr int Bn   = 16;
constexpr int Nn   = 2048;
constexpr int Fin  = 8;
constexpr int Kn   = 35;
constexpr int NODES = Bn * Nn;          // 32768
constexpr int EDG   = NODES * Kn;       // 1146880
constexpr int NSTATB = 1024;            // stats grid blocks
constexpr float EPSV = 1e-5f;

// ---- monotone float<->u32 encoding for ordered compare / atomic max ----
__device__ __forceinline__ unsigned enc_f(float f){
    unsigned u = __float_as_uint(f);
    return (u & 0x80000000u) ? ~u : (u | 0x80000000u);
}
__device__ __forceinline__ float dec_f(unsigned e){
    unsigned u = (e & 0x80000000u) ? (e ^ 0x80000000u) : ~e;
    return __uint_as_float(u);
}

// ---- squared norms per node ----
template<int C>
__global__ __launch_bounds__(256) void sq_kernel(const float* __restrict__ h, float* __restrict__ sq){
    int i = blockIdx.x * 256 + threadIdx.x;
    if (i >= NODES) return;
    const float* p = h + (size_t)i * C;
    float s = 0.f;
#pragma unroll
    for (int c = 0; c < C; c++) s += p[c] * p[c];
    sq[i] = s;
}

// ---- kNN: 4 queries per block; block-wide dist phase, per-wave threshold search.
// Stats-seeded bracket (mu/sigma 4-pivot seed) + ballot+popc counting.
// Finds the exact set of Kn smallest (dist, index) keys == top_k set.
template<int C>
__global__ __launch_bounds__(256, 3) void knn_kernel(const float* __restrict__ h, const float* __restrict__ sq,
                                                     int* __restrict__ idxout){
    __shared__ float dist[4][Nn];                 // 32 KB
    __shared__ float hi4[4][C];
    __shared__ float sqi[4];
    __shared__ unsigned long long keybuf[4][64];  // 2 KB: boundary-band keys
    int t  = threadIdx.x;
    int b  = blockIdx.x >> 9;               // Nn/4 = 512 blocks per batch
    int i0 = (blockIdx.x & 511) * 4;

    for (int i = t; i < 4 * C; i += 256)
        hi4[i / C][i % C] = h[((size_t)(b * Nn) + i0 + i / C) * C + (i % C)];
    if (t < 4) sqi[t] = sq[b * Nn + i0 + t];
    __syncthreads();

    for (int j = t; j < Nn; j += 256){
        const float4* hj = (const float4*)(h + ((size_t)(b * Nn) + j) * C);
        float d0 = 0.f, d1 = 0.f, d2 = 0.f, d3 = 0.f;
#pragma unroll
        for (int c4 = 0; c4 < C / 4; c4++){
            float4 v = hj[c4];
            d0 += hi4[0][4*c4] * v.x + hi4[0][4*c4+1] * v.y + hi4[0][4*c4+2] * v.z + hi4[0][4*c4+3] * v.w;
            d1 += hi4[1][4*c4] * v.x + hi4[1][4*c4+1] * v.y + hi4[1][4*c4+2] * v.z + hi4[1][4*c4+3] * v.w;
            d2 += hi4[2][4*c4] * v.x + hi4[2][4*c4+1] * v.y + hi4[2][4*c4+2] * v.z + hi4[2][4*c4+3] * v.w;
            d3 += hi4[3][4*c4] * v.x + hi4[3][4*c4+1] * v.y + hi4[3][4*c4+2] * v.z + hi4[3][4*c4+3] * v.w;
        }
        float sj = sq[b * Nn + j];
        dist[0][j] = sqi[0] + sj - 2.f * d0;
        dist[1][j] = sqi[1] + sj - 2.f * d1;
        dist[2][j] = sqi[2] + sj - 2.f * d2;
        dist[3][j] = sqi[3] + sj - 2.f * d3;
    }
    __syncthreads();

    // ---- per-wave select: wave w handles query i0+w; value j=s*64+lane in dv[s] ----
    int w = t >> 6, lane = t & 63;
    float dv[32];
#pragma unroll
    for (int s = 0; s < 32; s++) dv[s] = dist[w][s * 64 + lane];

    // one-time wave stats: min, max, sum, sumsq (4 independent shuffle chains)
    float lmin = dv[0], lmax = dv[0], lsum = 0.f, lssq = 0.f;
#pragma unroll
    for (int s = 0; s < 32; s++){
        float v = dv[s];
        lmin = fminf(lmin, v); lmax = fmaxf(lmax, v);
        lsum += v; lssq += v * v;
    }
#pragma unroll
    for (int d = 1; d < 64; d <<= 1){
        lmin = fminf(lmin, __shfl_xor(lmin, d));
        lmax = fmaxf(lmax, __shfl_xor(lmax, d));
        lsum += __shfl_xor(lsum, d);
        lssq += __shfl_xor(lssq, d);
    }
    float mu = lsum * (1.f / (float)Nn);
    float sg = sqrtf(fmaxf(lssq * (1.f / (float)Nn) - mu * mu, 0.f));

    // bracket invariant: count(<lo)=clo <= Kn < chi=count(<hi)
    float lo = lmin;
    float hi = lmax + fmaxf(fabsf(lmax) * 1e-5f, 1e-6f);
    int clo = 0, chi = Nn;

    // seed pass: 4 pivots around the Kn/Nn quantile (z ~ -2.12), one sweep
    {
        float pv0 = mu - 2.6f * sg, pv1 = mu - 2.2f * sg, pv2 = mu - 1.9f * sg, pv3 = mu - 1.6f * sg;
        int c0 = 0, c1 = 0, c2 = 0, c3 = 0;
#pragma unroll
        for (int s = 0; s < 32; s++){
            float v = dv[s];
            c0 += __popcll(__ballot(v < pv0));
            c1 += __popcll(__ballot(v < pv1));
            c2 += __popcll(__ballot(v < pv2));
            c3 += __popcll(__ballot(v < pv3));
        }
        if (c0 <= Kn){ if (pv0 > lo){ lo = pv0; clo = c0; } } else { if (pv0 < hi){ hi = pv0; chi = c0; } }
        if (c1 <= Kn){ if (pv1 > lo){ lo = pv1; clo = c1; } } else { if (pv1 < hi){ hi = pv1; chi = c1; } }
        if (c2 <= Kn){ if (pv2 > lo){ lo = pv2; clo = c2; } } else { if (pv2 < hi){ hi = pv2; chi = c2; } }
        if (c3 <= Kn){ if (pv3 > lo){ lo = pv3; clo = c3; } } else { if (pv3 < hi){ hi = pv3; chi = c3; } }
    }

    // refinement: hybrid interpolation/bisection, counts via ballot+popc
    for (int it = 0; it < 16; it++){
        if (clo == Kn || chi - clo <= 24) break;
        float piv;
        if (it & 1) piv = 0.5f * (lo + hi);
        else        piv = lo + (hi - lo) * (((float)(Kn - clo) + 0.5f) / (float)(chi - clo));
        if (!(piv > lo && piv < hi)) piv = 0.5f * (lo + hi);
        if (!(piv > lo && piv < hi)) break;   // ulp-stalled (ties): band handles it
        int c = 0;
#pragma unroll
        for (int s = 0; s < 32; s++) c += __popcll(__ballot(dv[s] < piv));
        if (c <= Kn){ lo = piv; clo = c; } else { hi = piv; chi = c; }
    }

    unsigned below = 0u, band = 0u;
#pragma unroll
    for (int s = 0; s < 32; s++){
        float v = dv[s];
        below |= (v < lo)            ? (1u << s) : 0u;
        band  |= (v >= lo && v < hi) ? (1u << s) : 0u;
    }
    int r  = Kn - clo;        // picks needed from band
    int bc = chi - clo;       // band population (wave-wide, exact)

    size_t obase = ((size_t)(b * Nn) + i0 + w) * Kn;
    unsigned long long me_lower = (1ull << lane) - 1ull;

    // write definite selections [0, clo) via ballot compaction
    int off = 0;
#pragma unroll
    for (int s = 0; s < 32; s++){
        unsigned long long m = __ballot((below >> s) & 1);
        if ((below >> s) & 1){
            int o = off + __popcll(m & me_lower);
            idxout[obase + o] = s * 64 + lane;
        }
        off += __popcll(m);
    }

    if (r > 0){
        if (bc <= 64){
            // compact band keys into LDS via ballots
            int boff = 0;
#pragma unroll
            for (int s = 0; s < 32; s++){
                unsigned long long m = __ballot((band >> s) & 1);
                if ((band >> s) & 1){
                    int o = boff + __popcll(m & me_lower);
                    keybuf[w][o] = (((unsigned long long)enc_f(dv[s])) << 16) | (unsigned)(s * 64 + lane);
                }
                boff += __popcll(m);
            }
            // lane c ranks key c against all bc keys (broadcast LDS reads)
            if (lane < bc){
                unsigned long long myk = keybuf[w][lane];
                int rank = 0;
                for (int j2 = 0; j2 < bc; j2++) rank += (keybuf[w][j2] < myk) ? 1 : 0;
                if (rank < r) idxout[obase + clo + rank] = (int)(myk & 0xffffu);
            }
        } else {
            // rare fallback (heavy ties / stalled search): iterative wave-min extraction
            unsigned bm = band;
            for (int e = 0; e < r; e++){
                unsigned long long best = ~0ull;
                unsigned tmp = bm;
                while (tmp){
                    int s = __ffs(tmp) - 1; tmp &= tmp - 1;
                    unsigned long long key = (((unsigned long long)enc_f(dv[s])) << 16) | (unsigned)(s * 64 + lane);
                    best = (key < best) ? key : best;
                }
                unsigned long long wmin = best;
#pragma unroll
                for (int d = 1; d < 64; d <<= 1){
                    unsigned long long ov = __shfl_xor(wmin, d);
                    wmin = (ov < wmin) ? ov : wmin;
                }
                if (best == wmin && best != ~0ull){
                    int j2 = (int)(wmin & 0xffffu);
                    bm &= ~(1u << (j2 >> 6));
                    idxout[obase + clo + e] = j2;
                }
            }
        }
    }
}

// ---- pre1: p = x@(W1a-W1b)+b1, q = x@W1b  (layer-1 factorization) ----
__global__ __launch_bounds__(256) void pre1_kernel(const float* __restrict__ x,
        const float* __restrict__ w1, const float* __restrict__ b1,
        float* __restrict__ p, float* __restrict__ q){
    int t = threadIdx.x, w = t >> 6, c = t & 63;
    float wd[8], wb[8];
#pragma unroll
    for (int f = 0; f < 8; f++){
        float wbv = w1[(8 + f) * 64 + c];
        wb[f] = wbv;
        wd[f] = w1[f * 64 + c] - wbv;
    }
    float b1c = b1[c];
    int slot = blockIdx.x * 4 + w;                 // 2048 slots
    for (int it = 0; it < 16; it++){
        int node = slot + it * 2048;
        const float* xp = x + (size_t)node * Fin;
        float pv = b1c, qv = 0.f;
#pragma unroll
        for (int f = 0; f < 8; f++){
            float xv = xp[f];
            pv += xv * wd[f]; qv += xv * wb[f];
        }
        p[(size_t)node * 64 + c] = pv;
        q[(size_t)node * 64 + c] = qv;
    }
}

// ---- stats pass 1: moments of z1 = p[i]+q[j] over edges ----
__global__ __launch_bounds__(256) void stats1_kernel(const float* __restrict__ p, const float* __restrict__ q,
        const int* __restrict__ idx, float* __restrict__ sumP, float* __restrict__ ssqP){
    __shared__ float red[2][4][64];
    int t = threadIdx.x, w = t >> 6, c = t & 63;
    float s = 0.f, ss = 0.f;
    int slot = blockIdx.x * 4 + w;                 // 4096 slots
    for (int it = 0; it < 8; it++){
        int node = slot + it * 4096;
        int b = node >> 11;
        float pc = p[(size_t)node * 64 + c];
        const int* ip = idx + (size_t)node * Kn;
        for (int k = 0; k < Kn; k++){
            int j = ip[k];
            float z = pc + q[((size_t)(b << 11) + j) * 64 + c];
            s += z; ss += z * z;
        }
    }
    red[0][w][c] = s; red[1][w][c] = ss;
    __syncthreads();
    if (w == 0){
        sumP[blockIdx.x * 64 + c] = red[0][0][c] + red[0][1][c] + red[0][2][c] + red[0][3][c];
        ssqP[blockIdx.x * 64 + c] = red[1][0][c] + red[1][1][c] + red[1][2][c] + red[1][3][c];
    }
}

// ---- finalize BN params from partials ----
__global__ void finalize_kernel(const float* __restrict__ sumP, const float* __restrict__ ssqP,
        const float* __restrict__ gg, const float* __restrict__ bt,
        float* __restrict__ scale, float* __restrict__ shift, float inv_count){
    int c = threadIdx.x;   // 64 threads
    float s = 0.f, q = 0.f;
    for (int i = 0; i < NSTATB; i++){ s += sumP[i * 64 + c]; q += ssqP[i * 64 + c]; }
    float mu  = s * inv_count;
    float var = q * inv_count - mu * mu;
    float sc  = gg[c] / sqrtf(var + EPSV);
    scale[c] = sc;
    shift[c] = bt[c] - mu * sc;
}

// ---- stats pass 2: z1 -> bn1+relu -> z2 (64x64 matvec, weights in regs), moments ----
__global__ __launch_bounds__(256) void stats2_kernel(const float* __restrict__ p, const float* __restrict__ q,
        const int* __restrict__ idx,
        const float* __restrict__ sc1v, const float* __restrict__ sh1v,
        const float* __restrict__ w2, const float* __restrict__ b2,
        float* __restrict__ sumP, float* __restrict__ ssqP){
    __shared__ float hsh[4][2][64];
    __shared__ float red[2][4][64];
    int t = threadIdx.x, w = t >> 6, c = t & 63;
    float w2c[64];
#pragma unroll
    for (int f = 0; f < 64; f++) w2c[f] = w2[f * 64 + c];
    float sc1 = sc1v[c], sh1 = sh1v[c], b2c = b2[c];
    float s = 0.f, ss = 0.f;
    int slot = blockIdx.x * 4 + w;
    for (int it = 0; it < 8; it++){
        int node = slot + it * 4096;
        int b = node >> 11;
        float pc = p[(size_t)node * 64 + c];
        const int* ip = idx + (size_t)node * Kn;
        for (int k = 0; k < Kn; k++){
            int j = ip[k];
            float z = pc + q[((size_t)(b << 11) + j) * 64 + c];
            float h1 = fmaxf(0.f, z * sc1 + sh1);
            hsh[w][k & 1][c] = h1;
            const float4* h4 = (const float4*)hsh[w][k & 1];
            float z2 = b2c;
#pragma unroll
            for (int f4 = 0; f4 < 16; f4++){
                float4 hv = h4[f4];
                z2 += hv.x * w2c[4*f4] + hv.y * w2c[4*f4+1] + hv.z * w2c[4*f4+2] + hv.w * w2c[4*f4+3];
            }
            s += z2; ss += z2 * z2;
        }
    }
    red[0][w][c] = s; red[1][w][c] = ss;
    __syncthreads();
    if (w == 0){
        sumP[blockIdx.x * 64 + c] = red[0][0][c] + red[0][1][c] + red[0][2][c] + red[0][3][c];
        ssqP[blockIdx.x * 64 + c] = red[1][0][c] + red[1][1][c] + red[1][2][c] + red[1][3][c];
    }
}

// ---- conv1: wave-per-node, layers 2/3 as register-weight matvecs, max over k ----
__global__ __launch_bounds__(256) void conv1_kernel(const float* __restrict__ p, const float* __restrict__ q,
        const int* __restrict__ idx,
        const float* __restrict__ sc1v, const float* __restrict__ sh1v,
        const float* __restrict__ w2, const float* __restrict__ b2,
        const float* __restrict__ sc2v, const float* __restrict__ sh2v,
        const float* __restrict__ w3, const float* __restrict__ b3,
        float* __restrict__ x1){
    __shared__ float hA[4][2][64];
    __shared__ float hB[4][2][64];
    int t = threadIdx.x, w = t >> 6, c = t & 63;
    float w2c[64], w3c[64];
#pragma unroll
    for (int f = 0; f < 64; f++){ w2c[f] = w2[f * 64 + c]; w3c[f] = w3[f * 64 + c]; }
    float sc1 = sc1v[c], sh1 = sh1v[c], sc2 = sc2v[c], sh2 = sh2v[c];
    float b2c = b2[c], b3c = b3[c];
    int node = blockIdx.x * 4 + w;
    int b = node >> 11;
    float pc = p[(size_t)node * 64 + c];
    const int* ip = idx + (size_t)node * Kn;
    float acc = -FLT_MAX;
    for (int k = 0; k < Kn; k++){
        int j = ip[k];
        float z = pc + q[((size_t)(b << 11) + j) * 64 + c];
        float h1 = fmaxf(0.f, z * sc1 + sh1);
        hA[w][k & 1][c] = h1;
        const float4* h4 = (const float4*)hA[w][k & 1];
        float z2 = b2c;
#pragma unroll
        for (int f4 = 0; f4 < 16; f4++){
            float4 hv = h4[f4];
            z2 += hv.x * w2c[4*f4] + hv.y * w2c[4*f4+1] + hv.z * w2c[4*f4+2] + hv.w * w2c[4*f4+3];
        }
        float h2 = fmaxf(0.f, z2 * sc2 + sh2);
        hB[w][k & 1][c] = h2;
        const float4* g4 = (const float4*)hB[w][k & 1];
        float z3 = b3c;
#pragma unroll
        for (int f4 = 0; f4 < 16; f4++){
            float4 hv = g4[f4];
            z3 += hv.x * w3c[4*f4] + hv.y * w3c[4*f4+1] + hv.z * w3c[4*f4+2] + hv.w * w3c[4*f4+3];
        }
        acc = fmaxf(acc, z3);
    }
    x1[(size_t)node * 64 + c] = acc;
}

// ---- pre2: u = x1@(W4a-W4b)+b4 (into x2 buffer), v = x1@W4b ----
__global__ __launch_bounds__(256) void pre2_kernel(const float* __restrict__ x1,
        const float* __restrict__ w4, const float* __restrict__ b4,
        float* __restrict__ u, float* __restrict__ v){
    __shared__ float x1s[16][64];
    int t = threadIdx.x;
    int c = t & 127, h = t >> 7;
    float wd[64], wb[64];
#pragma unroll
    for (int f = 0; f < 64; f++){
        float wbv = w4[(64 + f) * 128 + c];
        wb[f] = wbv;
        wd[f] = w4[f * 128 + c] - wbv;
    }
    float b4c = b4[c];
    int base = blockIdx.x * 16;
    for (int i = t; i < 16 * 64; i += 256)
        x1s[i >> 6][i & 63] = x1[(size_t)(base + (i >> 6)) * 64 + (i & 63)];
    __syncthreads();
    for (int n = 0; n < 8; n++){
        int node = base + h * 8 + n;
        const float4* xr = (const float4*)x1s[h * 8 + n];
        float uv = b4c, vv = 0.f;
#pragma unroll
        for (int f4 = 0; f4 < 16; f4++){
            float4 xv = xr[f4];
            uv += xv.x * wd[4*f4] + xv.y * wd[4*f4+1] + xv.z * wd[4*f4+2] + xv.w * wd[4*f4+3];
            vv += xv.x * wb[4*f4] + xv.y * wb[4*f4+1] + xv.z * wb[4*f4+2] + xv.w * wb[4*f4+3];
        }
        u[(size_t)node * 128 + c] = uv;
        v[(size_t)node * 128 + c] = vv;
    }
}

// ---- gmax2: x2[i][c] = u[i][c] + max_k v[j_k][c]  (x2 holds u on entry) ----
__global__ __launch_bounds__(256) void gmax2_kernel(const float* __restrict__ v, const int* __restrict__ idx,
        float* __restrict__ x2){
    int t = threadIdx.x, g = t >> 7, c = t & 127;
    int node = blockIdx.x * 2 + g;
    int b = node >> 11;
    const int* ip = idx + (size_t)node * Kn;
    float vm = -FLT_MAX;
    for (int k = 0; k < Kn; k++){
        int j = ip[k];
        vm = fmaxf(vm, v[((size_t)(b << 11) + j) * 128 + c]);
    }
    x2[(size_t)node * 128 + c] += vm;
}

// ---- out = cat(x1,x2) @ w5 + b5, global max over nodes (encoded atomics) ----
__global__ __launch_bounds__(256) void outpool_kernel(const float* __restrict__ x1, const float* __restrict__ x2,
        const float* __restrict__ w5, const float* __restrict__ b5, unsigned* __restrict__ pooled){
    __shared__ float rows[8][192];
    int t = threadIdx.x;
    int node0 = blockIdx.x * 8;
    for (int i = t; i < 8 * 192; i += 256){
        int e = i / 192, f = i - e * 192;
        int nd = node0 + e;
        rows[e][f] = (f < 64) ? x1[(size_t)nd * 64 + f] : x2[(size_t)nd * 128 + f - 64];
    }
    __syncthreads();
    float z[8];
#pragma unroll
    for (int e = 0; e < 8; e++) z[e] = b5[t];
    for (int f = 0; f < 192; f++){
        float w = w5[f * 256 + t];
#pragma unroll
        for (int e = 0; e < 8; e++) z[e] += rows[e][f] * w;
    }
    float m = z[0];
#pragma unroll
    for (int e = 1; e < 8; e++) m = fmaxf(m, z[e]);
    int b = node0 >> 11;
    atomicMax(&pooled[b * 256 + t], enc_f(m));
}

// ---- head: decode pooled, MLP [256,128,64,4] with training-mode BN over 16 ----
__global__ __launch_bounds__(256) void head_kernel(const unsigned* __restrict__ pooledE,
        const float* __restrict__ w6, const float* __restrict__ b6, const float* __restrict__ g6, const float* __restrict__ bt6,
        const float* __restrict__ w7, const float* __restrict__ b7, const float* __restrict__ g7, const float* __restrict__ bt7,
        const float* __restrict__ w8, const float* __restrict__ b8, float* __restrict__ out){
    __shared__ float P[16][256];
    __shared__ float H6[16][128];
    __shared__ float H7[16][64];
    int t = threadIdx.x;
    for (int i = t; i < 16 * 256; i += 256) P[i >> 8][i & 255] = dec_f(pooledE[i]);
    __syncthreads();
    for (int i = t; i < 16 * 128; i += 256){
        int r = i >> 7, c = i & 127;
        float z = b6[c];
        for (int f = 0; f < 256; f++) z += P[r][f] * w6[f * 128 + c];
        H6[r][c] = z;
    }
    __syncthreads();
    if (t < 128){
        float s = 0.f, q = 0.f;
        for (int r = 0; r < 16; r++){ float v = H6[r][t]; s += v; q += v * v; }
        float mu = s * (1.f / 16.f);
        float var = q * (1.f / 16.f) - mu * mu;
        float sc = g6[t] / sqrtf(var + EPSV);
        float sh = bt6[t] - mu * sc;
        for (int r = 0; r < 16; r++) H6[r][t] = fmaxf(0.f, H6[r][t] * sc + sh);
    }
    __syncthreads();
    for (int i = t; i < 16 * 64; i += 256){
        int r = i >> 6, c = i & 63;
        float z = b7[c];
        for (int f = 0; f < 128; f++) z += H6[r][f] * w7[f * 64 + c];
        H7[r][c] = z;
    }
    __syncthreads();
    if (t < 64){
        float s = 0.f, q = 0.f;
        for (int r = 0; r < 16; r++){ float v = H7[r][t]; s += v; q += v * v; }
        float mu = s * (1.f / 16.f);
        float var = q * (1.f / 16.f) - mu * mu;
        float sc = g7[t] / sqrtf(var + EPSV);
        float sh = bt7[t] - mu * sc;
        for (int r = 0; r < 16; r++) H7[r][t] = fmaxf(0.f, H7[r][t] * sc + sh);
    }
    __syncthreads();
    if (t < 64){
        int r = t >> 2, c = t & 3;
        float z = b8[c];
        for (int f = 0; f < 64; f++) z += H7[r][f] * w8[f * 4 + c];
        out[t] = z;
    }
}

extern "C" void kernel_launch(void* const* d_in, const int* in_sizes, int n_in,
                              void* d_out, int out_size, void* d_ws, size_t ws_size,
                              hipStream_t stream){
    const float* x   = (const float*)d_in[0];
    const float* w1  = (const float*)d_in[1];
    const float* b1  = (const float*)d_in[2];
    const float* g1  = (const float*)d_in[3];
    const float* bt1 = (const float*)d_in[4];
    const float* w2  = (const float*)d_in[5];
    const float* b2  = (const float*)d_in[6];
    const float* g2  = (const float*)d_in[7];
    const float* bt2 = (const float*)d_in[8];
    const float* w3  = (const float*)d_in[9];
    const float* b3  = (const float*)d_in[10];
    const float* w4  = (const float*)d_in[11];
    const float* b4  = (const float*)d_in[12];
    const float* w5  = (const float*)d_in[13];
    const float* b5  = (const float*)d_in[14];
    const float* w6  = (const float*)d_in[15];
    const float* b6  = (const float*)d_in[16];
    const float* g6  = (const float*)d_in[17];
    const float* bt6 = (const float*)d_in[18];
    const float* w7  = (const float*)d_in[19];
    const float* b7  = (const float*)d_in[20];
    const float* g7  = (const float*)d_in[21];
    const float* bt7 = (const float*)d_in[22];
    const float* w8  = (const float*)d_in[23];
    const float* b8  = (const float*)d_in[24];
    float* out = (float*)d_out;

    char* ws = (char*)d_ws;
    size_t off = 0;
    auto alloc = [&](size_t bytes)->char*{
        char* p = ws + off;
        off += (bytes + 255) & ~(size_t)255;
        return p;
    };
    int*      idx1   = (int*)alloc((size_t)EDG * 4);
    int*      idx2   = (int*)alloc((size_t)EDG * 4);
    float*    sq1    = (float*)alloc((size_t)NODES * 4);
    float*    sq2    = (float*)alloc((size_t)NODES * 4);
    float*    x1     = (float*)alloc((size_t)NODES * 64 * 4);
    float*    x2     = (float*)alloc((size_t)NODES * 128 * 4);
    float*    sumP   = (float*)alloc((size_t)NSTATB * 64 * 4);
    float*    ssqP   = (float*)alloc((size_t)NSTATB * 64 * 4);
    float*    scale1 = (float*)alloc(64 * 4);
    float*    shift1 = (float*)alloc(64 * 4);
    float*    scale2 = (float*)alloc(64 * 4);
    float*    shift2 = (float*)alloc(64 * 4);
    unsigned* pooled = (unsigned*)alloc((size_t)Bn * 256 * 4);
    float*    p      = (float*)alloc((size_t)NODES * 64 * 4);
    float*    q      = (float*)alloc((size_t)NODES * 64 * 4);
    float*    v      = p;   // overlay: p,q are dead once conv1 finishes; v = 128 floats/node spans p+q

    hipMemsetAsync(pooled, 0, (size_t)Bn * 256 * 4, stream);

    sq_kernel<8><<<(NODES + 255) / 256, 256, 0, stream>>>(x, sq1);
    knn_kernel<8><<<NODES / 4, 256, 0, stream>>>(x, sq1, idx1);
    pre1_kernel<<<512, 256, 0, stream>>>(x, w1, b1, p, q);
    stats1_kernel<<<NSTATB, 256, 0, stream>>>(p, q, idx1, sumP, ssqP);
    finalize_kernel<<<1, 64, 0, stream>>>(sumP, ssqP, g1, bt1, scale1, shift1, 1.0f / (float)EDG);
    stats2_kernel<<<NSTATB, 256, 0, stream>>>(p, q, idx1, scale1, shift1, w2, b2, sumP, ssqP);
    finalize_kernel<<<1, 64, 0, stream>>>(sumP, ssqP, g2, bt2, scale2, shift2, 1.0f / (float)EDG);
    conv1_kernel<<<NODES / 4, 256, 0, stream>>>(p, q, idx1, scale1, shift1,
                                                w2, b2, scale2, shift2, w3, b3, x1);
    sq_kernel<64><<<(NODES + 255) / 256, 256, 0, stream>>>(x1, sq2);
    knn_kernel<64><<<NODES / 4, 256, 0, stream>>>(x1, sq2, idx2);
    pre2_kernel<<<NODES / 16, 256, 0, stream>>>(x1, w4, b4, x2, v);
    gmax2_kernel<<<NODES / 2, 256, 0, stream>>>(v, idx2, x2);
    outpool_kernel<<<NODES / 8, 256, 0, stream>>>(x1, x2, w5, b5, pooled);
    head_kernel<<<1, 256, 0, stream>>>(pooled, w6, b6, g6, bt6, w7, b7, g7, bt7, w8, b8, out);
}

// Round 8
// 2252.652 us; speedup vs baseline: 1.3504x; 1.3504x over previous
//
#include <hip/hip_runtime.h>
#include <cfloat>
#include <cstdint>

// Problem constants
constexpr int Bn   = 16;
constexpr int Nn   = 2048;
constexpr int Fin  = 8;
constexpr int Kn   = 35;
constexpr int NODES = Bn * Nn;          // 32768
constexpr int EDG   = NODES * Kn;       // 1146880
constexpr int NSTATB = 1024;            // stats grid blocks
constexpr float EPSV = 1e-5f;

// ---- monotone float<->u32 encoding for ordered compare / atomic max ----
__device__ __forceinline__ unsigned enc_f(float f){
    unsigned u = __float_as_uint(f);
    return (u & 0x80000000u) ? ~u : (u | 0x80000000u);
}
__device__ __forceinline__ float dec_f(unsigned e){
    unsigned u = (e & 0x80000000u) ? (e ^ 0x80000000u) : ~e;
    return __uint_as_float(u);
}

// ---- squared norms per node ----
template<int C>
__global__ __launch_bounds__(256) void sq_kernel(const float* __restrict__ h, float* __restrict__ sq){
    int i = blockIdx.x * 256 + threadIdx.x;
    if (i >= NODES) return;
    const float* p = h + (size_t)i * C;
    float s = 0.f;
#pragma unroll
    for (int c = 0; c < C; c++) s += p[c] * p[c];
    sq[i] = s;
}

// ---- kNN: 4 queries per block; block-wide dist phase, per-wave threshold search.
// Stats-seeded bracket (mu/sigma 4-pivot seed) + ballot+popc counting.
// NOTE: no min-waves launch bound — r7 showed capping VGPR to 84 spills dv[32]
// to scratch (FETCH 33MB -> 4.4GB, 2x slower). 148 VGPR / default is right.
template<int C>
__global__ __launch_bounds__(256) void knn_kernel(const float* __restrict__ h, const float* __restrict__ sq,
                                                  int* __restrict__ idxout){
    __shared__ float dist[4][Nn];                 // 32 KB
    __shared__ float hi4[4][C];
    __shared__ float sqi[4];
    __shared__ unsigned long long keybuf[4][64];  // 2 KB: boundary-band keys
    int t  = threadIdx.x;
    int b  = blockIdx.x >> 9;               // Nn/4 = 512 blocks per batch
    int i0 = (blockIdx.x & 511) * 4;

    for (int i = t; i < 4 * C; i += 256)
        hi4[i / C][i % C] = h[((size_t)(b * Nn) + i0 + i / C) * C + (i % C)];
    if (t < 4) sqi[t] = sq[b * Nn + i0 + t];
    __syncthreads();

    for (int j = t; j < Nn; j += 256){
        const float4* hj = (const float4*)(h + ((size_t)(b * Nn) + j) * C);
        float d0 = 0.f, d1 = 0.f, d2 = 0.f, d3 = 0.f;
#pragma unroll
        for (int c4 = 0; c4 < C / 4; c4++){
            float4 v = hj[c4];
            d0 += hi4[0][4*c4] * v.x + hi4[0][4*c4+1] * v.y + hi4[0][4*c4+2] * v.z + hi4[0][4*c4+3] * v.w;
            d1 += hi4[1][4*c4] * v.x + hi4[1][4*c4+1] * v.y + hi4[1][4*c4+2] * v.z + hi4[1][4*c4+3] * v.w;
            d2 += hi4[2][4*c4] * v.x + hi4[2][4*c4+1] * v.y + hi4[2][4*c4+2] * v.z + hi4[2][4*c4+3] * v.w;
            d3 += hi4[3][4*c4] * v.x + hi4[3][4*c4+1] * v.y + hi4[3][4*c4+2] * v.z + hi4[3][4*c4+3] * v.w;
        }
        float sj = sq[b * Nn + j];
        dist[0][j] = sqi[0] + sj - 2.f * d0;
        dist[1][j] = sqi[1] + sj - 2.f * d1;
        dist[2][j] = sqi[2] + sj - 2.f * d2;
        dist[3][j] = sqi[3] + sj - 2.f * d3;
    }
    __syncthreads();

    // ---- per-wave select: wave w handles query i0+w; value j=s*64+lane in dv[s] ----
    int w = t >> 6, lane = t & 63;
    float dv[32];
#pragma unroll
    for (int s = 0; s < 32; s++) dv[s] = dist[w][s * 64 + lane];

    // one-time wave stats: min, max, sum, sumsq (4 independent shuffle chains)
    float lmin = dv[0], lmax = dv[0], lsum = 0.f, lssq = 0.f;
#pragma unroll
    for (int s = 0; s < 32; s++){
        float v = dv[s];
        lmin = fminf(lmin, v); lmax = fmaxf(lmax, v);
        lsum += v; lssq += v * v;
    }
#pragma unroll
    for (int d = 1; d < 64; d <<= 1){
        lmin = fminf(lmin, __shfl_xor(lmin, d));
        lmax = fmaxf(lmax, __shfl_xor(lmax, d));
        lsum += __shfl_xor(lsum, d);
        lssq += __shfl_xor(lssq, d);
    }
    float mu = lsum * (1.f / (float)Nn);
    float sg = sqrtf(fmaxf(lssq * (1.f / (float)Nn) - mu * mu, 0.f));

    // bracket invariant: count(<lo)=clo <= Kn < chi=count(<hi)
    float lo = lmin;
    float hi = lmax + fmaxf(fabsf(lmax) * 1e-5f, 1e-6f);
    int clo = 0, chi = Nn;

    // seed pass: 4 pivots around the Kn/Nn quantile (z ~ -2.12), one sweep
    {
        float pv0 = mu - 2.6f * sg, pv1 = mu - 2.2f * sg, pv2 = mu - 1.9f * sg, pv3 = mu - 1.6f * sg;
        int c0 = 0, c1 = 0, c2 = 0, c3 = 0;
#pragma unroll
        for (int s = 0; s < 32; s++){
            float v = dv[s];
            c0 += __popcll(__ballot(v < pv0));
            c1 += __popcll(__ballot(v < pv1));
            c2 += __popcll(__ballot(v < pv2));
            c3 += __popcll(__ballot(v < pv3));
        }
        if (c0 <= Kn){ if (pv0 > lo){ lo = pv0; clo = c0; } } else { if (pv0 < hi){ hi = pv0; chi = c0; } }
        if (c1 <= Kn){ if (pv1 > lo){ lo = pv1; clo = c1; } } else { if (pv1 < hi){ hi = pv1; chi = c1; } }
        if (c2 <= Kn){ if (pv2 > lo){ lo = pv2; clo = c2; } } else { if (pv2 < hi){ hi = pv2; chi = c2; } }
        if (c3 <= Kn){ if (pv3 > lo){ lo = pv3; clo = c3; } } else { if (pv3 < hi){ hi = pv3; chi = c3; } }
    }

    // refinement: hybrid interpolation/bisection, counts via ballot+popc
    for (int it = 0; it < 16; it++){
        if (clo == Kn || chi - clo <= 24) break;
        float piv;
        if (it & 1) piv = 0.5f * (lo + hi);
        else        piv = lo + (hi - lo) * (((float)(Kn - clo) + 0.5f) / (float)(chi - clo));
        if (!(piv > lo && piv < hi)) piv = 0.5f * (lo + hi);
        if (!(piv > lo && piv < hi)) break;   // ulp-stalled (ties): band handles it
        int c = 0;
#pragma unroll
        for (int s = 0; s < 32; s++) c += __popcll(__ballot(dv[s] < piv));
        if (c <= Kn){ lo = piv; clo = c; } else { hi = piv; chi = c; }
    }

    unsigned below = 0u, band = 0u;
#pragma unroll
    for (int s = 0; s < 32; s++){
        float v = dv[s];
        below |= (v < lo)            ? (1u << s) : 0u;
        band  |= (v >= lo && v < hi) ? (1u << s) : 0u;
    }
    int r  = Kn - clo;        // picks needed from band
    int bc = chi - clo;       // band population (wave-wide, exact)

    size_t obase = ((size_t)(b * Nn) + i0 + w) * Kn;
    unsigned long long me_lower = (1ull << lane) - 1ull;

    // write definite selections [0, clo) via ballot compaction
    int off = 0;
#pragma unroll
    for (int s = 0; s < 32; s++){
        unsigned long long m = __ballot((below >> s) & 1);
        if ((below >> s) & 1){
            int o = off + __popcll(m & me_lower);
            idxout[obase + o] = s * 64 + lane;
        }
        off += __popcll(m);
    }

    if (r > 0){
        if (bc <= 64){
            // compact band keys into LDS via ballots
            int boff = 0;
#pragma unroll
            for (int s = 0; s < 32; s++){
                unsigned long long m = __ballot((band >> s) & 1);
                if ((band >> s) & 1){
                    int o = boff + __popcll(m & me_lower);
                    keybuf[w][o] = (((unsigned long long)enc_f(dv[s])) << 16) | (unsigned)(s * 64 + lane);
                }
                boff += __popcll(m);
            }
            // lane c ranks key c against all bc keys (broadcast LDS reads)
            if (lane < bc){
                unsigned long long myk = keybuf[w][lane];
                int rank = 0;
                for (int j2 = 0; j2 < bc; j2++) rank += (keybuf[w][j2] < myk) ? 1 : 0;
                if (rank < r) idxout[obase + clo + rank] = (int)(myk & 0xffffu);
            }
        } else {
            // rare fallback (heavy ties / stalled search): iterative wave-min extraction
            unsigned bm = band;
            for (int e = 0; e < r; e++){
                unsigned long long best = ~0ull;
                unsigned tmp = bm;
                while (tmp){
                    int s = __ffs(tmp) - 1; tmp &= tmp - 1;
                    unsigned long long key = (((unsigned long long)enc_f(dv[s])) << 16) | (unsigned)(s * 64 + lane);
                    best = (key < best) ? key : best;
                }
                unsigned long long wmin = best;
#pragma unroll
                for (int d = 1; d < 64; d <<= 1){
                    unsigned long long ov = __shfl_xor(wmin, d);
                    wmin = (ov < wmin) ? ov : wmin;
                }
                if (best == wmin && best != ~0ull){
                    int j2 = (int)(wmin & 0xffffu);
                    bm &= ~(1u << (j2 >> 6));
                    idxout[obase + clo + e] = j2;
                }
            }
        }
    }
}

// ---- pre1: p = x@(W1a-W1b)+b1, q = x@W1b  (layer-1 factorization) ----
__global__ __launch_bounds__(256) void pre1_kernel(const float* __restrict__ x,
        const float* __restrict__ w1, const float* __restrict__ b1,
        float* __restrict__ p, float* __restrict__ q){
    int t = threadIdx.x, w = t >> 6, c = t & 63;
    float wd[8], wb[8];
#pragma unroll
    for (int f = 0; f < 8; f++){
        float wbv = w1[(8 + f) * 64 + c];
        wb[f] = wbv;
        wd[f] = w1[f * 64 + c] - wbv;
    }
    float b1c = b1[c];
    int slot = blockIdx.x * 4 + w;                 // 2048 slots
    for (int it = 0; it < 16; it++){
        int node = slot + it * 2048;
        const float* xp = x + (size_t)node * Fin;
        float pv = b1c, qv = 0.f;
#pragma unroll
        for (int f = 0; f < 8; f++){
            float xv = xp[f];
            pv += xv * wd[f]; qv += xv * wb[f];
        }
        p[(size_t)node * 64 + c] = pv;
        q[(size_t)node * 64 + c] = qv;
    }
}

// ---- stats pass 1: moments of z1 = p[i]+q[j] over edges ----
__global__ __launch_bounds__(256) void stats1_kernel(const float* __restrict__ p, const float* __restrict__ q,
        const int* __restrict__ idx, float* __restrict__ sumP, float* __restrict__ ssqP){
    __shared__ float red[2][4][64];
    int t = threadIdx.x, w = t >> 6, c = t & 63;
    float s = 0.f, ss = 0.f;
    int slot = blockIdx.x * 4 + w;                 // 4096 slots
    for (int it = 0; it < 8; it++){
        int node = slot + it * 4096;
        int b = node >> 11;
        float pc = p[(size_t)node * 64 + c];
        const int* ip = idx + (size_t)node * Kn;
        for (int k = 0; k < Kn; k++){
            int j = ip[k];
            float z = pc + q[((size_t)(b << 11) + j) * 64 + c];
            s += z; ss += z * z;
        }
    }
    red[0][w][c] = s; red[1][w][c] = ss;
    __syncthreads();
    if (w == 0){
        sumP[blockIdx.x * 64 + c] = red[0][0][c] + red[0][1][c] + red[0][2][c] + red[0][3][c];
        ssqP[blockIdx.x * 64 + c] = red[1][0][c] + red[1][1][c] + red[1][2][c] + red[1][3][c];
    }
}

// ---- finalize BN params from partials ----
__global__ void finalize_kernel(const float* __restrict__ sumP, const float* __restrict__ ssqP,
        const float* __restrict__ gg, const float* __restrict__ bt,
        float* __restrict__ scale, float* __restrict__ shift, float inv_count){
    int c = threadIdx.x;   // 64 threads
    float s = 0.f, q = 0.f;
    for (int i = 0; i < NSTATB; i++){ s += sumP[i * 64 + c]; q += ssqP[i * 64 + c]; }
    float mu  = s * inv_count;
    float var = q * inv_count - mu * mu;
    float sc  = gg[c] / sqrtf(var + EPSV);
    scale[c] = sc;
    shift[c] = bt[c] - mu * sc;
}

// ---- stats pass 2: z1 -> bn1+relu -> z2 (64x64 matvec, weights in regs), moments ----
__global__ __launch_bounds__(256) void stats2_kernel(const float* __restrict__ p, const float* __restrict__ q,
        const int* __restrict__ idx,
        const float* __restrict__ sc1v, const float* __restrict__ sh1v,
        const float* __restrict__ w2, const float* __restrict__ b2,
        float* __restrict__ sumP, float* __restrict__ ssqP){
    __shared__ float hsh[4][2][64];
    __shared__ float red[2][4][64];
    int t = threadIdx.x, w = t >> 6, c = t & 63;
    float w2c[64];
#pragma unroll
    for (int f = 0; f < 64; f++) w2c[f] = w2[f * 64 + c];
    float sc1 = sc1v[c], sh1 = sh1v[c], b2c = b2[c];
    float s = 0.f, ss = 0.f;
    int slot = blockIdx.x * 4 + w;
    for (int it = 0; it < 8; it++){
        int node = slot + it * 4096;
        int b = node >> 11;
        float pc = p[(size_t)node * 64 + c];
        const int* ip = idx + (size_t)node * Kn;
        for (int k = 0; k < Kn; k++){
            int j = ip[k];
            float z = pc + q[((size_t)(b << 11) + j) * 64 + c];
            float h1 = fmaxf(0.f, z * sc1 + sh1);
            hsh[w][k & 1][c] = h1;
            const float4* h4 = (const float4*)hsh[w][k & 1];
            float z2 = b2c;
#pragma unroll
            for (int f4 = 0; f4 < 16; f4++){
                float4 hv = h4[f4];
                z2 += hv.x * w2c[4*f4] + hv.y * w2c[4*f4+1] + hv.z * w2c[4*f4+2] + hv.w * w2c[4*f4+3];
            }
            s += z2; ss += z2 * z2;
        }
    }
    red[0][w][c] = s; red[1][w][c] = ss;
    __syncthreads();
    if (w == 0){
        sumP[blockIdx.x * 64 + c] = red[0][0][c] + red[0][1][c] + red[0][2][c] + red[0][3][c];
        ssqP[blockIdx.x * 64 + c] = red[1][0][c] + red[1][1][c] + red[1][2][c] + red[1][3][c];
    }
}

// ---- conv1: wave-per-node, layers 2/3 as register-weight matvecs, max over k ----
__global__ __launch_bounds__(256) void conv1_kernel(const float* __restrict__ p, const float* __restrict__ q,
        const int* __restrict__ idx,
        const float* __restrict__ sc1v, const float* __restrict__ sh1v,
        const float* __restrict__ w2, const float* __restrict__ b2,
        const float* __restrict__ sc2v, const float* __restrict__ sh2v,
        const float* __restrict__ w3, const float* __restrict__ b3,
        float* __restrict__ x1){
    __shared__ float hA[4][2][64];
    __shared__ float hB[4][2][64];
    int t = threadIdx.x, w = t >> 6, c = t & 63;
    float w2c[64], w3c[64];
#pragma unroll
    for (int f = 0; f < 64; f++){ w2c[f] = w2[f * 64 + c]; w3c[f] = w3[f * 64 + c]; }
    float sc1 = sc1v[c], sh1 = sh1v[c], sc2 = sc2v[c], sh2 = sh2v[c];
    float b2c = b2[c], b3c = b3[c];
    int node = blockIdx.x * 4 + w;
    int b = node >> 11;
    float pc = p[(size_t)node * 64 + c];
    const int* ip = idx + (size_t)node * Kn;
    float acc = -FLT_MAX;
    for (int k = 0; k < Kn; k++){
        int j = ip[k];
        float z = pc + q[((size_t)(b << 11) + j) * 64 + c];
        float h1 = fmaxf(0.f, z * sc1 + sh1);
        hA[w][k & 1][c] = h1;
        const float4* h4 = (const float4*)hA[w][k & 1];
        float z2 = b2c;
#pragma unroll
        for (int f4 = 0; f4 < 16; f4++){
            float4 hv = h4[f4];
            z2 += hv.x * w2c[4*f4] + hv.y * w2c[4*f4+1] + hv.z * w2c[4*f4+2] + hv.w * w2c[4*f4+3];
        }
        float h2 = fmaxf(0.f, z2 * sc2 + sh2);
        hB[w][k & 1][c] = h2;
        const float4* g4 = (const float4*)hB[w][k & 1];
        float z3 = b3c;
#pragma unroll
        for (int f4 = 0; f4 < 16; f4++){
            float4 hv = g4[f4];
            z3 += hv.x * w3c[4*f4] + hv.y * w3c[4*f4+1] + hv.z * w3c[4*f4+2] + hv.w * w3c[4*f4+3];
        }
        acc = fmaxf(acc, z3);
    }
    x1[(size_t)node * 64 + c] = acc;
}

// ---- pre2: u = x1@(W4a-W4b)+b4 (into x2 buffer), v = x1@W4b ----
__global__ __launch_bounds__(256) void pre2_kernel(const float* __restrict__ x1,
        const float* __restrict__ w4, const float* __restrict__ b4,
        float* __restrict__ u, float* __restrict__ v){
    __shared__ float x1s[16][64];
    int t = threadIdx.x;
    int c = t & 127, h = t >> 7;
    float wd[64], wb[64];
#pragma unroll
    for (int f = 0; f < 64; f++){
        float wbv = w4[(64 + f) * 128 + c];
        wb[f] = wbv;
        wd[f] = w4[f * 128 + c] - wbv;
    }
    float b4c = b4[c];
    int base = blockIdx.x * 16;
    for (int i = t; i < 16 * 64; i += 256)
        x1s[i >> 6][i & 63] = x1[(size_t)(base + (i >> 6)) * 64 + (i & 63)];
    __syncthreads();
    for (int n = 0; n < 8; n++){
        int node = base + h * 8 + n;
        const float4* xr = (const float4*)x1s[h * 8 + n];
        float uv = b4c, vv = 0.f;
#pragma unroll
        for (int f4 = 0; f4 < 16; f4++){
            float4 xv = xr[f4];
            uv += xv.x * wd[4*f4] + xv.y * wd[4*f4+1] + xv.z * wd[4*f4+2] + xv.w * wd[4*f4+3];
            vv += xv.x * wb[4*f4] + xv.y * wb[4*f4+1] + xv.z * wb[4*f4+2] + xv.w * wb[4*f4+3];
        }
        u[(size_t)node * 128 + c] = uv;
        v[(size_t)node * 128 + c] = vv;
    }
}

// ---- gmax2: x2[i][c] = u[i][c] + max_k v[j_k][c]  (x2 holds u on entry) ----
__global__ __launch_bounds__(256) void gmax2_kernel(const float* __restrict__ v, const int* __restrict__ idx,
        float* __restrict__ x2){
    int t = threadIdx.x, g = t >> 7, c = t & 127;
    int node = blockIdx.x * 2 + g;
    int b = node >> 11;
    const int* ip = idx + (size_t)node * Kn;
    float vm = -FLT_MAX;
    for (int k = 0; k < Kn; k++){
        int j = ip[k];
        vm = fmaxf(vm, v[((size_t)(b << 11) + j) * 128 + c]);
    }
    x2[(size_t)node * 128 + c] += vm;
}

// ---- out = cat(x1,x2) @ w5 + b5, global max over nodes (encoded atomics) ----
__global__ __launch_bounds__(256) void outpool_kernel(const float* __restrict__ x1, const float* __restrict__ x2,
        const float* __restrict__ w5, const float* __restrict__ b5, unsigned* __restrict__ pooled){
    __shared__ float rows[8][192];
    int t = threadIdx.x;
    int node0 = blockIdx.x * 8;
    for (int i = t; i < 8 * 192; i += 256){
        int e = i / 192, f = i - e * 192;
        int nd = node0 + e;
        rows[e][f] = (f < 64) ? x1[(size_t)nd * 64 + f] : x2[(size_t)nd * 128 + f - 64];
    }
    __syncthreads();
    float z[8];
#pragma unroll
    for (int e = 0; e < 8; e++) z[e] = b5[t];
    for (int f = 0; f < 192; f++){
        float w = w5[f * 256 + t];
#pragma unroll
        for (int e = 0; e < 8; e++) z[e] += rows[e][f] * w;
    }
    float m = z[0];
#pragma unroll
    for (int e = 1; e < 8; e++) m = fmaxf(m, z[e]);
    int b = node0 >> 11;
    atomicMax(&pooled[b * 256 + t], enc_f(m));
}

// ---- head: decode pooled, MLP [256,128,64,4] with training-mode BN over 16 ----
__global__ __launch_bounds__(256) void head_kernel(const unsigned* __restrict__ pooledE,
        const float* __restrict__ w6, const float* __restrict__ b6, const float* __restrict__ g6, const float* __restrict__ bt6,
        const float* __restrict__ w7, const float* __restrict__ b7, const float* __restrict__ g7, const float* __restrict__ bt7,
        const float* __restrict__ w8, const float* __restrict__ b8, float* __restrict__ out){
    __shared__ float P[16][256];
    __shared__ float H6[16][128];
    __shared__ float H7[16][64];
    int t = threadIdx.x;
    for (int i = t; i < 16 * 256; i += 256) P[i >> 8][i & 255] = dec_f(pooledE[i]);
    __syncthreads();
    for (int i = t; i < 16 * 128; i += 256){
        int r = i >> 7, c = i & 127;
        float z = b6[c];
        for (int f = 0; f < 256; f++) z += P[r][f] * w6[f * 128 + c];
        H6[r][c] = z;
    }
    __syncthreads();
    if (t < 128){
        float s = 0.f, q = 0.f;
        for (int r = 0; r < 16; r++){ float v = H6[r][t]; s += v; q += v * v; }
        float mu = s * (1.f / 16.f);
        float var = q * (1.f / 16.f) - mu * mu;
        float sc = g6[t] / sqrtf(var + EPSV);
        float sh = bt6[t] - mu * sc;
        for (int r = 0; r < 16; r++) H6[r][t] = fmaxf(0.f, H6[r][t] * sc + sh);
    }
    __syncthreads();
    for (int i = t; i < 16 * 64; i += 256){
        int r = i >> 6, c = i & 63;
        float z = b7[c];
        for (int f = 0; f < 128; f++) z += H6[r][f] * w7[f * 64 + c];
        H7[r][c] = z;
    }
    __syncthreads();
    if (t < 64){
        float s = 0.f, q = 0.f;
        for (int r = 0; r < 16; r++){ float v = H7[r][t]; s += v; q += v * v; }
        float mu = s * (1.f / 16.f);
        float var = q * (1.f / 16.f) - mu * mu;
        float sc = g7[t] / sqrtf(var + EPSV);
        float sh = bt7[t] - mu * sc;
        for (int r = 0; r < 16; r++) H7[r][t] = fmaxf(0.f, H7[r][t] * sc + sh);
    }
    __syncthreads();
    if (t < 64){
        int r = t >> 2, c = t & 3;
        float z = b8[c];
        for (int f = 0; f < 64; f++) z += H7[r][f] * w8[f * 4 + c];
        out[t] = z;
    }
}

extern "C" void kernel_launch(void* const* d_in, const int* in_sizes, int n_in,
                              void* d_out, int out_size, void* d_ws, size_t ws_size,
                              hipStream_t stream){
    const float* x   = (const float*)d_in[0];
    const float* w1  = (const float*)d_in[1];
    const float* b1  = (const float*)d_in[2];
    const float* g1  = (const float*)d_in[3];
    const float* bt1 = (const float*)d_in[4];
    const float* w2  = (const float*)d_in[5];
    const float* b2  = (const float*)d_in[6];
    const float* g2  = (const float*)d_in[7];
    const float* bt2 = (const float*)d_in[8];
    const float* w3  = (const float*)d_in[9];
    const float* b3  = (const float*)d_in[10];
    const float* w4  = (const float*)d_in[11];
    const float* b4  = (const float*)d_in[12];
    const float* w5  = (const float*)d_in[13];
    const float* b5  = (const float*)d_in[14];
    const float* w6  = (const float*)d_in[15];
    const float* b6  = (const float*)d_in[16];
    const float* g6  = (const float*)d_in[17];
    const float* bt6 = (const float*)d_in[18];
    const float* w7  = (const float*)d_in[19];
    const float* b7  = (const float*)d_in[20];
    const float* g7  = (const float*)d_in[21];
    const float* bt7 = (const float*)d_in[22];
    const float* w8  = (const float*)d_in[23];
    const float* b8  = (const float*)d_in[24];
    float* out = (float*)d_out;

    char* ws = (char*)d_ws;
    size_t off = 0;
    auto alloc = [&](size_t bytes)->char*{
        char* p = ws + off;
        off += (bytes + 255) & ~(size_t)255;
        return p;
    };
    int*      idx1   = (int*)alloc((size_t)EDG * 4);
    int*      idx2   = (int*)alloc((size_t)EDG * 4);
    float*    sq1    = (float*)alloc((size_t)NODES * 4);
    float*    sq2    = (float*)alloc((size_t)NODES * 4);
    float*    x1     = (float*)alloc((size_t)NODES * 64 * 4);
    float*    x2     = (float*)alloc((size_t)NODES * 128 * 4);
    float*    sumP   = (float*)alloc((size_t)NSTATB * 64 * 4);
    float*    ssqP   = (float*)alloc((size_t)NSTATB * 64 * 4);
    float*    scale1 = (float*)alloc(64 * 4);
    float*    shift1 = (float*)alloc(64 * 4);
    float*    scale2 = (float*)alloc(64 * 4);
    float*    shift2 = (float*)alloc(64 * 4);
    unsigned* pooled = (unsigned*)alloc((size_t)Bn * 256 * 4);
    float*    p      = (float*)alloc((size_t)NODES * 64 * 4);
    float*    q      = (float*)alloc((size_t)NODES * 64 * 4);
    float*    v      = p;   // overlay: p,q are dead once conv1 finishes; v = 128 floats/node spans p+q

    hipMemsetAsync(pooled, 0, (size_t)Bn * 256 * 4, stream);

    sq_kernel<8><<<(NODES + 255) / 256, 256, 0, stream>>>(x, sq1);
    knn_kernel<8><<<NODES / 4, 256, 0, stream>>>(x, sq1, idx1);
    pre1_kernel<<<512, 256, 0, stream>>>(x, w1, b1, p, q);
    stats1_kernel<<<NSTATB, 256, 0, stream>>>(p, q, idx1, sumP, ssqP);
    finalize_kernel<<<1, 64, 0, stream>>>(sumP, ssqP, g1, bt1, scale1, shift1, 1.0f / (float)EDG);
    stats2_kernel<<<NSTATB, 256, 0, stream>>>(p, q, idx1, scale1, shift1, w2, b2, sumP, ssqP);
    finalize_kernel<<<1, 64, 0, stream>>>(sumP, ssqP, g2, bt2, scale2, shift2, 1.0f / (float)EDG);
    conv1_kernel<<<NODES / 4, 256, 0, stream>>>(p, q, idx1, scale1, shift1,
                                                w2, b2, scale2, shift2, w3, b3, x1);
    sq_kernel<64><<<(NODES + 255) / 256, 256, 0, stream>>>(x1, sq2);
    knn_kernel<64><<<NODES / 4, 256, 0, stream>>>(x1, sq2, idx2);
    pre2_kernel<<<NODES / 16, 256, 0, stream>>>(x1, w4, b4, x2, v);
    gmax2_kernel<<<NODES / 2, 256, 0, stream>>>(v, idx2, x2);
    outpool_kernel<<<NODES / 8, 256, 0, stream>>>(x1, x2, w5, b5, pooled);
    head_kernel<<<1, 256, 0, stream>>>(pooled, w6, b6, g6, bt6, w7, b7, g7, bt7, w8, b8, out);
}

// Round 9
// 2039.188 us; speedup vs baseline: 1.4918x; 1.1047x over previous
//
#include <hip/hip_runtime.h>
#include <cfloat>
#include <cstdint>

// Problem constants
constexpr int Bn   = 16;
constexpr int Nn   = 2048;
constexpr int Fin  = 8;
constexpr int Kn   = 35;
constexpr int NODES = Bn * Nn;          // 32768
constexpr int EDG   = NODES * Kn;       // 1146880
constexpr int NSTATB = 1024;            // stats grid blocks
constexpr float EPSV = 1e-5f;

// ---- monotone float<->u32 encoding for ordered compare / atomic max ----
__device__ __forceinline__ unsigned enc_f(float f){
    unsigned u = __float_as_uint(f);
    return (u & 0x80000000u) ? ~u : (u | 0x80000000u);
}
__device__ __forceinline__ float dec_f(unsigned e){
    unsigned u = (e & 0x80000000u) ? (e ^ 0x80000000u) : ~e;
    return __uint_as_float(u);
}

// ---- squared norms per node ----
template<int C>
__global__ __launch_bounds__(256) void sq_kernel(const float* __restrict__ h, float* __restrict__ sq){
    int i = blockIdx.x * 256 + threadIdx.x;
    if (i >= NODES) return;
    const float* p = h + (size_t)i * C;
    float s = 0.f;
#pragma unroll
    for (int c = 0; c < C; c++) s += p[c] * p[c];
    sq[i] = s;
}

// ---- kNN: 4 queries per block; block-wide dist phase, per-wave select.
// Select: stats -> seeded threshold (chi<=128) -> LDS compact -> broadcast rank.
// dist values stay in LDS (no dv[32] registers: r7 showed spills are fatal;
// keeping VGPR <=128 doubles occupancy). Exact top_k set semantics.
template<int C>
__global__ __launch_bounds__(256) void knn_kernel(const float* __restrict__ h, const float* __restrict__ sq,
                                                  int* __restrict__ idxout){
    __shared__ float dist[4][Nn];                  // 32 KB
    __shared__ float hi4[4][C];
    __shared__ float sqi[4];
    __shared__ unsigned long long keybuf[4][128];  // 4 KB candidate keys
    int t  = threadIdx.x;
    int b  = blockIdx.x >> 9;               // Nn/4 = 512 blocks per batch
    int i0 = (blockIdx.x & 511) * 4;

    for (int i = t; i < 4 * C; i += 256)
        hi4[i / C][i % C] = h[((size_t)(b * Nn) + i0 + i / C) * C + (i % C)];
    if (t < 4) sqi[t] = sq[b * Nn + i0 + t];
    __syncthreads();

    for (int j = t; j < Nn; j += 256){
        const float4* hj = (const float4*)(h + ((size_t)(b * Nn) + j) * C);
        float d0 = 0.f, d1 = 0.f, d2 = 0.f, d3 = 0.f;
#pragma unroll
        for (int c4 = 0; c4 < C / 4; c4++){
            float4 v = hj[c4];
            d0 += hi4[0][4*c4] * v.x + hi4[0][4*c4+1] * v.y + hi4[0][4*c4+2] * v.z + hi4[0][4*c4+3] * v.w;
            d1 += hi4[1][4*c4] * v.x + hi4[1][4*c4+1] * v.y + hi4[1][4*c4+2] * v.z + hi4[1][4*c4+3] * v.w;
            d2 += hi4[2][4*c4] * v.x + hi4[2][4*c4+1] * v.y + hi4[2][4*c4+2] * v.z + hi4[2][4*c4+3] * v.w;
            d3 += hi4[3][4*c4] * v.x + hi4[3][4*c4+1] * v.y + hi4[3][4*c4+2] * v.z + hi4[3][4*c4+3] * v.w;
        }
        float sj = sq[b * Nn + j];
        dist[0][j] = sqi[0] + sj - 2.f * d0;
        dist[1][j] = sqi[1] + sj - 2.f * d1;
        dist[2][j] = sqi[2] + sj - 2.f * d2;
        dist[3][j] = sqi[3] + sj - 2.f * d3;
    }
    __syncthreads();

    // ---- per-wave select: wave w handles query i0+w; values read from LDS ----
    int w = t >> 6, lane = t & 63;
    const float* dw = dist[w];

    // stats sweep: min/max/sum/sumsq + wave reduce
    float lmin = FLT_MAX, lmax = -FLT_MAX, lsum = 0.f, lssq = 0.f;
#pragma unroll
    for (int s = 0; s < 32; s++){
        float v = dw[s * 64 + lane];
        lmin = fminf(lmin, v); lmax = fmaxf(lmax, v);
        lsum += v; lssq += v * v;
    }
#pragma unroll
    for (int d = 1; d < 64; d <<= 1){
        lmin = fminf(lmin, __shfl_xor(lmin, d));
        lmax = fmaxf(lmax, __shfl_xor(lmax, d));
        lsum += __shfl_xor(lsum, d);
        lssq += __shfl_xor(lssq, d);
    }
    float mu = lsum * (1.f / (float)Nn);
    float sg = sqrtf(fmaxf(lssq * (1.f / (float)Nn) - mu * mu, 0.f));

    // bracket: lo/clo guide interpolation only; hi/chi exact (chi = count(<hi))
    float lo = lmin;  int clo = 0;
    float hi = lmax + fmaxf(fabsf(lmax) * 1e-5f, 1e-6f);  int chi = Nn;

    // seed sweep: 4 pivots spanning Gaussian(-2.12) and chi-square-skew(-1.3) quantiles
    {
        float pv0 = mu - 2.5f * sg, pv1 = mu - 1.9f * sg, pv2 = mu - 1.45f * sg, pv3 = mu - 1.1f * sg;
        int c0 = 0, c1 = 0, c2 = 0, c3 = 0;
#pragma unroll
        for (int s = 0; s < 32; s++){
            float v = dw[s * 64 + lane];
            c0 += __popcll(__ballot(v < pv0));
            c1 += __popcll(__ballot(v < pv1));
            c2 += __popcll(__ballot(v < pv2));
            c3 += __popcll(__ballot(v < pv3));
        }
        if (c0 >= Kn){ if (pv0 < hi){ hi = pv0; chi = c0; } } else { if (pv0 > lo){ lo = pv0; clo = c0; } }
        if (c1 >= Kn){ if (pv1 < hi){ hi = pv1; chi = c1; } } else { if (pv1 > lo){ lo = pv1; clo = c1; } }
        if (c2 >= Kn){ if (pv2 < hi){ hi = pv2; chi = c2; } } else { if (pv2 > lo){ lo = pv2; clo = c2; } }
        if (c3 >= Kn){ if (pv3 < hi){ hi = pv3; chi = c3; } } else { if (pv3 > lo){ lo = pv3; clo = c3; } }
    }

    // refine (usually 0 iterations): dual-pivot interpolation+bisection until chi<=128
    for (int it = 0; it < 32 && chi > 128; it++){
        float pb = 0.5f * (lo + hi);
        float pa = lo + (hi - lo) * (((float)(96 - clo)) / (float)(chi - clo));
        if (!(pa > lo && pa < hi)) pa = pb;
        if (!(pb > lo && pb < hi)) break;   // ulp-collapsed (massive ties): fallback
        int ca = 0, cb = 0;
#pragma unroll
        for (int s = 0; s < 32; s++){
            float v = dw[s * 64 + lane];
            ca += __popcll(__ballot(v < pa));
            cb += __popcll(__ballot(v < pb));
        }
        if (ca >= Kn){ if (pa < hi){ hi = pa; chi = ca; } } else { if (pa > lo){ lo = pa; clo = ca; } }
        if (cb >= Kn){ if (pb < hi){ hi = pb; chi = cb; } } else { if (pb > lo){ lo = pb; clo = cb; } }
    }

    size_t obase = ((size_t)(b * Nn) + i0 + w) * Kn;

    if (chi <= 128){
        // pad keybuf, then compact all candidates (< hi) via ballot offsets
        keybuf[w][lane]      = ~0ull;
        keybuf[w][lane + 64] = ~0ull;
        unsigned long long me_lower = (1ull << lane) - 1ull;
        int boff = 0;
#pragma unroll
        for (int s = 0; s < 32; s++){
            float v = dw[s * 64 + lane];
            bool cnd = v < hi;
            unsigned long long m = __ballot(cnd);
            if (cnd){
                int o = boff + __popcll(m & me_lower);
                keybuf[w][o] = (((unsigned long long)enc_f(v)) << 16) | (unsigned)(s * 64 + lane);
            }
            boff += __popcll(m);
        }
        // rank my two keys against all chi keys (broadcast LDS reads, unroll 8)
        unsigned long long k0 = keybuf[w][lane];
        unsigned long long k1 = keybuf[w][lane + 64];
        int r0 = 0, r1 = 0;
        int nR = (chi + 7) & ~7;          // <= 128; padding keys are ~0ull
        for (int j2 = 0; j2 < nR; j2 += 8){
            unsigned long long a0 = keybuf[w][j2+0], a1 = keybuf[w][j2+1];
            unsigned long long a2 = keybuf[w][j2+2], a3 = keybuf[w][j2+3];
            unsigned long long a4 = keybuf[w][j2+4], a5 = keybuf[w][j2+5];
            unsigned long long a6 = keybuf[w][j2+6], a7 = keybuf[w][j2+7];
            r0 += (a0<k0)+(a1<k0)+(a2<k0)+(a3<k0)+(a4<k0)+(a5<k0)+(a6<k0)+(a7<k0);
            r1 += (a0<k1)+(a1<k1)+(a2<k1)+(a3<k1)+(a4<k1)+(a5<k1)+(a6<k1)+(a7<k1);
        }
        if (lane < chi      && r0 < Kn) idxout[obase + r0] = (int)(k0 & 0xffffu);
        if (lane + 64 < chi && r1 < Kn) idxout[obase + r1] = (int)(k1 & 0xffffu);
    } else {
        // exact fallback (pathological ties only): iterative wave-min extraction
        unsigned selmask = 0u;
        for (int e = 0; e < Kn; e++){
            unsigned long long best = ~0ull;
#pragma unroll
            for (int s = 0; s < 32; s++){
                float v = dw[s * 64 + lane];
                if (v < hi && !((selmask >> s) & 1)){
                    unsigned long long key = (((unsigned long long)enc_f(v)) << 16) | (unsigned)(s * 64 + lane);
                    best = (key < best) ? key : best;
                }
            }
#pragma unroll
            for (int d = 1; d < 64; d <<= 1){
                unsigned long long ov = __shfl_xor(best, d);
                best = (ov < best) ? ov : best;
            }
            int jj = (int)(best & 0xffffu);
            if ((jj & 63) == lane) selmask |= 1u << (jj >> 6);
            if (lane == 0) idxout[obase + e] = jj;
        }
    }
}

// ---- pre1: p = x@(W1a-W1b)+b1, q = x@W1b  (layer-1 factorization) ----
__global__ __launch_bounds__(256) void pre1_kernel(const float* __restrict__ x,
        const float* __restrict__ w1, const float* __restrict__ b1,
        float* __restrict__ p, float* __restrict__ q){
    int t = threadIdx.x, w = t >> 6, c = t & 63;
    float wd[8], wb[8];
#pragma unroll
    for (int f = 0; f < 8; f++){
        float wbv = w1[(8 + f) * 64 + c];
        wb[f] = wbv;
        wd[f] = w1[f * 64 + c] - wbv;
    }
    float b1c = b1[c];
    int slot = blockIdx.x * 4 + w;                 // 2048 slots
    for (int it = 0; it < 16; it++){
        int node = slot + it * 2048;
        const float* xp = x + (size_t)node * Fin;
        float pv = b1c, qv = 0.f;
#pragma unroll
        for (int f = 0; f < 8; f++){
            float xv = xp[f];
            pv += xv * wd[f]; qv += xv * wb[f];
        }
        p[(size_t)node * 64 + c] = pv;
        q[(size_t)node * 64 + c] = qv;
    }
}

// ---- stats pass 1: moments of z1 = p[i]+q[j] over edges ----
__global__ __launch_bounds__(256) void stats1_kernel(const float* __restrict__ p, const float* __restrict__ q,
        const int* __restrict__ idx, float* __restrict__ sumP, float* __restrict__ ssqP){
    __shared__ float red[2][4][64];
    int t = threadIdx.x, w = t >> 6, c = t & 63;
    float s = 0.f, ss = 0.f;
    int slot = blockIdx.x * 4 + w;                 // 4096 slots
    for (int it = 0; it < 8; it++){
        int node = slot + it * 4096;
        int b = node >> 11;
        float pc = p[(size_t)node * 64 + c];
        const int* ip = idx + (size_t)node * Kn;
        for (int k = 0; k < Kn; k++){
            int j = ip[k];
            float z = pc + q[((size_t)(b << 11) + j) * 64 + c];
            s += z; ss += z * z;
        }
    }
    red[0][w][c] = s; red[1][w][c] = ss;
    __syncthreads();
    if (w == 0){
        sumP[blockIdx.x * 64 + c] = red[0][0][c] + red[0][1][c] + red[0][2][c] + red[0][3][c];
        ssqP[blockIdx.x * 64 + c] = red[1][0][c] + red[1][1][c] + red[1][2][c] + red[1][3][c];
    }
}

// ---- finalize BN params from partials ----
__global__ void finalize_kernel(const float* __restrict__ sumP, const float* __restrict__ ssqP,
        const float* __restrict__ gg, const float* __restrict__ bt,
        float* __restrict__ scale, float* __restrict__ shift, float inv_count){
    int c = threadIdx.x;   // 64 threads
    float s = 0.f, q = 0.f;
    for (int i = 0; i < NSTATB; i++){ s += sumP[i * 64 + c]; q += ssqP[i * 64 + c]; }
    float mu  = s * inv_count;
    float var = q * inv_count - mu * mu;
    float sc  = gg[c] / sqrtf(var + EPSV);
    scale[c] = sc;
    shift[c] = bt[c] - mu * sc;
}

// ---- stats pass 2: z1 -> bn1+relu -> z2 (64x64 matvec, weights in regs), moments ----
__global__ __launch_bounds__(256) void stats2_kernel(const float* __restrict__ p, const float* __restrict__ q,
        const int* __restrict__ idx,
        const float* __restrict__ sc1v, const float* __restrict__ sh1v,
        const float* __restrict__ w2, const float* __restrict__ b2,
        float* __restrict__ sumP, float* __restrict__ ssqP){
    __shared__ float hsh[4][2][64];
    __shared__ float red[2][4][64];
    int t = threadIdx.x, w = t >> 6, c = t & 63;
    float w2c[64];
#pragma unroll
    for (int f = 0; f < 64; f++) w2c[f] = w2[f * 64 + c];
    float sc1 = sc1v[c], sh1 = sh1v[c], b2c = b2[c];
    float s = 0.f, ss = 0.f;
    int slot = blockIdx.x * 4 + w;
    for (int it = 0; it < 8; it++){
        int node = slot + it * 4096;
        int b = node >> 11;
        float pc = p[(size_t)node * 64 + c];
        const int* ip = idx + (size_t)node * Kn;
        for (int k = 0; k < Kn; k++){
            int j = ip[k];
            float z = pc + q[((size_t)(b << 11) + j) * 64 + c];
            float h1 = fmaxf(0.f, z * sc1 + sh1);
            hsh[w][k & 1][c] = h1;
            const float4* h4 = (const float4*)hsh[w][k & 1];
            float z2 = b2c;
#pragma unroll
            for (int f4 = 0; f4 < 16; f4++){
                float4 hv = h4[f4];
                z2 += hv.x * w2c[4*f4] + hv.y * w2c[4*f4+1] + hv.z * w2c[4*f4+2] + hv.w * w2c[4*f4+3];
            }
            s += z2; ss += z2 * z2;
        }
    }
    red[0][w][c] = s; red[1][w][c] = ss;
    __syncthreads();
    if (w == 0){
        sumP[blockIdx.x * 64 + c] = red[0][0][c] + red[0][1][c] + red[0][2][c] + red[0][3][c];
        ssqP[blockIdx.x * 64 + c] = red[1][0][c] + red[1][1][c] + red[1][2][c] + red[1][3][c];
    }
}

// ---- conv1: wave-per-node, layers 2/3 as register-weight matvecs, max over k ----
__global__ __launch_bounds__(256) void conv1_kernel(const float* __restrict__ p, const float* __restrict__ q,
        const int* __restrict__ idx,
        const float* __restrict__ sc1v, const float* __restrict__ sh1v,
        const float* __restrict__ w2, const float* __restrict__ b2,
        const float* __restrict__ sc2v, const float* __restrict__ sh2v,
        const float* __restrict__ w3, const float* __restrict__ b3,
        float* __restrict__ x1){
    __shared__ float hA[4][2][64];
    __shared__ float hB[4][2][64];
    int t = threadIdx.x, w = t >> 6, c = t & 63;
    float w2c[64], w3c[64];
#pragma unroll
    for (int f = 0; f < 64; f++){ w2c[f] = w2[f * 64 + c]; w3c[f] = w3[f * 64 + c]; }
    float sc1 = sc1v[c], sh1 = sh1v[c], sc2 = sc2v[c], sh2 = sh2v[c];
    float b2c = b2[c], b3c = b3[c];
    int node = blockIdx.x * 4 + w;
    int b = node >> 11;
    float pc = p[(size_t)node * 64 + c];
    const int* ip = idx + (size_t)node * Kn;
    float acc = -FLT_MAX;
    for (int k = 0; k < Kn; k++){
        int j = ip[k];
        float z = pc + q[((size_t)(b << 11) + j) * 64 + c];
        float h1 = fmaxf(0.f, z * sc1 + sh1);
        hA[w][k & 1][c] = h1;
        const float4* h4 = (const float4*)hA[w][k & 1];
        float z2 = b2c;
#pragma unroll
        for (int f4 = 0; f4 < 16; f4++){
            float4 hv = h4[f4];
            z2 += hv.x * w2c[4*f4] + hv.y * w2c[4*f4+1] + hv.z * w2c[4*f4+2] + hv.w * w2c[4*f4+3];
        }
        float h2 = fmaxf(0.f, z2 * sc2 + sh2);
        hB[w][k & 1][c] = h2;
        const float4* g4 = (const float4*)hB[w][k & 1];
        float z3 = b3c;
#pragma unroll
        for (int f4 = 0; f4 < 16; f4++){
            float4 hv = g4[f4];
            z3 += hv.x * w3c[4*f4] + hv.y * w3c[4*f4+1] + hv.z * w3c[4*f4+2] + hv.w * w3c[4*f4+3];
        }
        acc = fmaxf(acc, z3);
    }
    x1[(size_t)node * 64 + c] = acc;
}

// ---- pre2: u = x1@(W4a-W4b)+b4 (into x2 buffer), v = x1@W4b ----
__global__ __launch_bounds__(256) void pre2_kernel(const float* __restrict__ x1,
        const float* __restrict__ w4, const float* __restrict__ b4,
        float* __restrict__ u, float* __restrict__ v){
    __shared__ float x1s[16][64];
    int t = threadIdx.x;
    int c = t & 127, h = t >> 7;
    float wd[64], wb[64];
#pragma unroll
    for (int f = 0; f < 64; f++){
        float wbv = w4[(64 + f) * 128 + c];
        wb[f] = wbv;
        wd[f] = w4[f * 128 + c] - wbv;
    }
    float b4c = b4[c];
    int base = blockIdx.x * 16;
    for (int i = t; i < 16 * 64; i += 256)
        x1s[i >> 6][i & 63] = x1[(size_t)(base + (i >> 6)) * 64 + (i & 63)];
    __syncthreads();
    for (int n = 0; n < 8; n++){
        int node = base + h * 8 + n;
        const float4* xr = (const float4*)x1s[h * 8 + n];
        float uv = b4c, vv = 0.f;
#pragma unroll
        for (int f4 = 0; f4 < 16; f4++){
            float4 xv = xr[f4];
            uv += xv.x * wd[4*f4] + xv.y * wd[4*f4+1] + xv.z * wd[4*f4+2] + xv.w * wd[4*f4+3];
            vv += xv.x * wb[4*f4] + xv.y * wb[4*f4+1] + xv.z * wb[4*f4+2] + xv.w * wb[4*f4+3];
        }
        u[(size_t)node * 128 + c] = uv;
        v[(size_t)node * 128 + c] = vv;
    }
}

// ---- gmax2: x2[i][c] = u[i][c] + max_k v[j_k][c]  (x2 holds u on entry) ----
__global__ __launch_bounds__(256) void gmax2_kernel(const float* __restrict__ v, const int* __restrict__ idx,
        float* __restrict__ x2){
    int t = threadIdx.x, g = t >> 7, c = t & 127;
    int node = blockIdx.x * 2 + g;
    int b = node >> 11;
    const int* ip = idx + (size_t)node * Kn;
    float vm = -FLT_MAX;
    for (int k = 0; k < Kn; k++){
        int j = ip[k];
        vm = fmaxf(vm, v[((size_t)(b << 11) + j) * 128 + c]);
    }
    x2[(size_t)node * 128 + c] += vm;
}

// ---- out = cat(x1,x2) @ w5 + b5, global max over nodes (encoded atomics) ----
__global__ __launch_bounds__(256) void outpool_kernel(const float* __restrict__ x1, const float* __restrict__ x2,
        const float* __restrict__ w5, const float* __restrict__ b5, unsigned* __restrict__ pooled){
    __shared__ float rows[8][192];
    int t = threadIdx.x;
    int node0 = blockIdx.x * 8;
    for (int i = t; i < 8 * 192; i += 256){
        int e = i / 192, f = i - e * 192;
        int nd = node0 + e;
        rows[e][f] = (f < 64) ? x1[(size_t)nd * 64 + f] : x2[(size_t)nd * 128 + f - 64];
    }
    __syncthreads();
    float z[8];
#pragma unroll
    for (int e = 0; e < 8; e++) z[e] = b5[t];
    for (int f = 0; f < 192; f++){
        float w = w5[f * 256 + t];
#pragma unroll
        for (int e = 0; e < 8; e++) z[e] += rows[e][f] * w;
    }
    float m = z[0];
#pragma unroll
    for (int e = 1; e < 8; e++) m = fmaxf(m, z[e]);
    int b = node0 >> 11;
    atomicMax(&pooled[b * 256 + t], enc_f(m));
}

// ---- head: decode pooled, MLP [256,128,64,4] with training-mode BN over 16 ----
__global__ __launch_bounds__(256) void head_kernel(const unsigned* __restrict__ pooledE,
        const float* __restrict__ w6, const float* __restrict__ b6, const float* __restrict__ g6, const float* __restrict__ bt6,
        const float* __restrict__ w7, const float* __restrict__ b7, const float* __restrict__ g7, const float* __restrict__ bt7,
        const float* __restrict__ w8, const float* __restrict__ b8, float* __restrict__ out){
    __shared__ float P[16][256];
    __shared__ float H6[16][128];
    __shared__ float H7[16][64];
    int t = threadIdx.x;
    for (int i = t; i < 16 * 256; i += 256) P[i >> 8][i & 255] = dec_f(pooledE[i]);
    __syncthreads();
    for (int i = t; i < 16 * 128; i += 256){
        int r = i >> 7, c = i & 127;
        float z = b6[c];
        for (int f = 0; f < 256; f++) z += P[r][f] * w6[f * 128 + c];
        H6[r][c] = z;
    }
    __syncthreads();
    if (t < 128){
        float s = 0.f, q = 0.f;
        for (int r = 0; r < 16; r++){ float v = H6[r][t]; s += v; q += v * v; }
        float mu = s * (1.f / 16.f);
        float var = q * (1.f / 16.f) - mu * mu;
        float sc = g6[t] / sqrtf(var + EPSV);
        float sh = bt6[t] - mu * sc;
        for (int r = 0; r < 16; r++) H6[r][t] = fmaxf(0.f, H6[r][t] * sc + sh);
    }
    __syncthreads();
    for (int i = t; i < 16 * 64; i += 256){
        int r = i >> 6, c = i & 63;
        float z = b7[c];
        for (int f = 0; f < 128; f++) z += H6[r][f] * w7[f * 64 + c];
        H7[r][c] = z;
    }
    __syncthreads();
    if (t < 64){
        float s = 0.f, q = 0.f;
        for (int r = 0; r < 16; r++){ float v = H7[r][t]; s += v; q += v * v; }
        float mu = s * (1.f / 16.f);
        float var = q * (1.f / 16.f) - mu * mu;
        float sc = g7[t] / sqrtf(var + EPSV);
        float sh = bt7[t] - mu * sc;
        for (int r = 0; r < 16; r++) H7[r][t] = fmaxf(0.f, H7[r][t] * sc + sh);
    }
    __syncthreads();
    if (t < 64){
        int r = t >> 2, c = t & 3;
        float z = b8[c];
        for (int f = 0; f < 64; f++) z += H7[r][f] * w8[f * 4 + c];
        out[t] = z;
    }
}

extern "C" void kernel_launch(void* const* d_in, const int* in_sizes, int n_in,
                              void* d_out, int out_size, void* d_ws, size_t ws_size,
                              hipStream_t stream){
    const float* x   = (const float*)d_in[0];
    const float* w1  = (const float*)d_in[1];
    const float* b1  = (const float*)d_in[2];
    const float* g1  = (const float*)d_in[3];
    const float* bt1 = (const float*)d_in[4];
    const float* w2  = (const float*)d_in[5];
    const float* b2  = (const float*)d_in[6];
    const float* g2  = (const float*)d_in[7];
    const float* bt2 = (const float*)d_in[8];
    const float* w3  = (const float*)d_in[9];
    const float* b3  = (const float*)d_in[10];
    const float* w4  = (const float*)d_in[11];
    const float* b4  = (const float*)d_in[12];
    const float* w5  = (const float*)d_in[13];
    const float* b5  = (const float*)d_in[14];
    const float* w6  = (const float*)d_in[15];
    const float* b6  = (const float*)d_in[16];
    const float* g6  = (const float*)d_in[17];
    const float* bt6 = (const float*)d_in[18];
    const float* w7  = (const float*)d_in[19];
    const float* b7  = (const float*)d_in[20];
    const float* g7  = (const float*)d_in[21];
    const float* bt7 = (const float*)d_in[22];
    const float* w8  = (const float*)d_in[23];
    const float* b8  = (const float*)d_in[24];
    float* out = (float*)d_out;

    char* ws = (char*)d_ws;
    size_t off = 0;
    auto alloc = [&](size_t bytes)->char*{
        char* p = ws + off;
        off += (bytes + 255) & ~(size_t)255;
        return p;
    };
    int*      idx1   = (int*)alloc((size_t)EDG * 4);
    int*      idx2   = (int*)alloc((size_t)EDG * 4);
    float*    sq1    = (float*)alloc((size_t)NODES * 4);
    float*    sq2    = (float*)alloc((size_t)NODES * 4);
    float*    x1     = (float*)alloc((size_t)NODES * 64 * 4);
    float*    x2     = (float*)alloc((size_t)NODES * 128 * 4);
    float*    sumP   = (float*)alloc((size_t)NSTATB * 64 * 4);
    float*    ssqP   = (float*)alloc((size_t)NSTATB * 64 * 4);
    float*    scale1 = (float*)alloc(64 * 4);
    float*    shift1 = (float*)alloc(64 * 4);
    float*    scale2 = (float*)alloc(64 * 4);
    float*    shift2 = (float*)alloc(64 * 4);
    unsigned* pooled = (unsigned*)alloc((size_t)Bn * 256 * 4);
    float*    p      = (float*)alloc((size_t)NODES * 64 * 4);
    float*    q      = (float*)alloc((size_t)NODES * 64 * 4);
    float*    v      = p;   // overlay: p,q are dead once conv1 finishes; v = 128 floats/node spans p+q

    hipMemsetAsync(pooled, 0, (size_t)Bn * 256 * 4, stream);

    sq_kernel<8><<<(NODES + 255) / 256, 256, 0, stream>>>(x, sq1);
    knn_kernel<8><<<NODES / 4, 256, 0, stream>>>(x, sq1, idx1);
    pre1_kernel<<<512, 256, 0, stream>>>(x, w1, b1, p, q);
    stats1_kernel<<<NSTATB, 256, 0, stream>>>(p, q, idx1, sumP, ssqP);
    finalize_kernel<<<1, 64, 0, stream>>>(sumP, ssqP, g1, bt1, scale1, shift1, 1.0f / (float)EDG);
    stats2_kernel<<<NSTATB, 256, 0, stream>>>(p, q, idx1, scale1, shift1, w2, b2, sumP, ssqP);
    finalize_kernel<<<1, 64, 0, stream>>>(sumP, ssqP, g2, bt2, scale2, shift2, 1.0f / (float)EDG);
    conv1_kernel<<<NODES / 4, 256, 0, stream>>>(p, q, idx1, scale1, shift1,
                                                w2, b2, scale2, shift2, w3, b3, x1);
    sq_kernel<64><<<(NODES + 255) / 256, 256, 0, stream>>>(x1, sq2);
    knn_kernel<64><<<NODES / 4, 256, 0, stream>>>(x1, sq2, idx2);
    pre2_kernel<<<NODES / 16, 256, 0, stream>>>(x1, w4, b4, x2, v);
    gmax2_kernel<<<NODES / 2, 256, 0, stream>>>(v, idx2, x2);
    outpool_kernel<<<NODES / 8, 256, 0, stream>>>(x1, x2, w5, b5, pooled);
    head_kernel<<<1, 256, 0, stream>>>(pooled, w6, b6, g6, bt6, w7, b7, g7, bt7, w8, b8, out);
}

// Round 10
// 1719.949 us; speedup vs baseline: 1.7686x; 1.1856x over previous
//
#include <hip/hip_runtime.h>
#include <cfloat>
#include <cstdint>

// Problem constants
constexpr int Bn   = 16;
constexpr int Nn   = 2048;
constexpr int Fin  = 8;
constexpr int Kn   = 35;
constexpr int NODES = Bn * Nn;          // 32768
constexpr int EDG   = NODES * Kn;       // 1146880
constexpr int NSTATB = 1024;            // stats grid blocks
constexpr float EPSV = 1e-5f;

// ---- monotone float<->u32 encoding for ordered compare / atomic max ----
__device__ __forceinline__ unsigned enc_f(float f){
    unsigned u = __float_as_uint(f);
    return (u & 0x80000000u) ? ~u : (u | 0x80000000u);
}
__device__ __forceinline__ float dec_f(unsigned e){
    unsigned u = (e & 0x80000000u) ? (e ^ 0x80000000u) : ~e;
    return __uint_as_float(u);
}

// ---- squared norms per node ----
template<int C>
__global__ __launch_bounds__(256) void sq_kernel(const float* __restrict__ h, float* __restrict__ sq){
    int i = blockIdx.x * 256 + threadIdx.x;
    if (i >= NODES) return;
    const float* p = h + (size_t)i * C;
    float s = 0.f;
#pragma unroll
    for (int c = 0; c < C; c++) s += p[c] * p[c];
    sq[i] = s;
}

// ---- kNN: 4 queries per block. Dist phase fuses per-query sum/sumsq stats.
// Select: seeded exact-count threshold (chi<=128) -> LDS compact -> broadcast rank.
// All sweep LDS reads batched 8-wide; query rows read as b128 broadcasts.
// Exact top_k set semantics (selection = exact counts vs exact threshold + rank).
template<int C>
__global__ __launch_bounds__(256) void knn_kernel(const float* __restrict__ h, const float* __restrict__ sq,
                                                  int* __restrict__ idxout){
    __shared__ float dist[4][Nn];                  // 32 KB
    __shared__ float hi4[4][C];
    __shared__ float sqi[4];
    __shared__ float statred[4][2][4];             // [query][sum|ssq][wave]
    __shared__ unsigned long long keybuf[4][128];  // 4 KB candidate keys
    int t  = threadIdx.x;
    int b  = blockIdx.x >> 9;               // Nn/4 = 512 blocks per batch
    int i0 = (blockIdx.x & 511) * 4;
    int w  = t >> 6, lane = t & 63;

    for (int i = t; i < 4 * C; i += 256)
        hi4[i / C][i % C] = h[((size_t)(b * Nn) + i0 + i / C) * C + (i % C)];
    if (t < 4) sqi[t] = sq[b * Nn + i0 + t];
    __syncthreads();

    // ---- dist phase with fused per-query sum/sumsq partials ----
    const float4* H0 = (const float4*)hi4[0];
    const float4* H1 = (const float4*)hi4[1];
    const float4* H2 = (const float4*)hi4[2];
    const float4* H3 = (const float4*)hi4[3];
    float ps0=0.f,ps1=0.f,ps2=0.f,ps3=0.f, pq0=0.f,pq1=0.f,pq2=0.f,pq3=0.f;
    for (int j = t; j < Nn; j += 256){
        const float4* hj = (const float4*)(h + ((size_t)(b * Nn) + j) * C);
        float d0 = 0.f, d1 = 0.f, d2 = 0.f, d3 = 0.f;
#pragma unroll 4
        for (int c4 = 0; c4 < C / 4; c4++){
            float4 v = hj[c4];
            float4 a0 = H0[c4], a1 = H1[c4], a2 = H2[c4], a3 = H3[c4];
            d0 += a0.x*v.x + a0.y*v.y + a0.z*v.z + a0.w*v.w;
            d1 += a1.x*v.x + a1.y*v.y + a1.z*v.z + a1.w*v.w;
            d2 += a2.x*v.x + a2.y*v.y + a2.z*v.z + a2.w*v.w;
            d3 += a3.x*v.x + a3.y*v.y + a3.z*v.z + a3.w*v.w;
        }
        float sj = sq[b * Nn + j];
        float D0 = sqi[0] + sj - 2.f*d0; dist[0][j] = D0; ps0 += D0; pq0 += D0*D0;
        float D1 = sqi[1] + sj - 2.f*d1; dist[1][j] = D1; ps1 += D1; pq1 += D1*D1;
        float D2 = sqi[2] + sj - 2.f*d2; dist[2][j] = D2; ps2 += D2; pq2 += D2*D2;
        float D3 = sqi[3] + sj - 2.f*d3; dist[3][j] = D3; ps3 += D3; pq3 += D3*D3;
    }
    // wave-reduce 8 partials (interleaved chains)
#pragma unroll
    for (int d = 1; d < 64; d <<= 1){
        ps0 += __shfl_xor(ps0, d); pq0 += __shfl_xor(pq0, d);
        ps1 += __shfl_xor(ps1, d); pq1 += __shfl_xor(pq1, d);
        ps2 += __shfl_xor(ps2, d); pq2 += __shfl_xor(pq2, d);
        ps3 += __shfl_xor(ps3, d); pq3 += __shfl_xor(pq3, d);
    }
    if (lane == 0){
        statred[0][0][w] = ps0; statred[0][1][w] = pq0;
        statred[1][0][w] = ps1; statred[1][1][w] = pq1;
        statred[2][0][w] = ps2; statred[2][1][w] = pq2;
        statred[3][0][w] = ps3; statred[3][1][w] = pq3;
    }
    __syncthreads();

    // ---- per-wave select: wave w handles query i0+w ----
    const float* dw = dist[w];
    float smu = statred[w][0][0] + statred[w][0][1] + statred[w][0][2] + statred[w][0][3];
    float sqq = statred[w][1][0] + statred[w][1][1] + statred[w][1][2] + statred[w][1][3];
    float mu = smu * (1.f / (float)Nn);
    float sg = sqrtf(fmaxf(sqq * (1.f / (float)Nn) - mu * mu, 0.f));

    float lo = mu - 8.f * sg;  int clo = 0;   // clo approximate (guides interpolation only)
    float hi = FLT_MAX;        int chi = Nn;  // exact: count(<FLT_MAX)=Nn (finite dists)

    // seed sweep: 5 pivots (4 around the k/N quantile + 1 safety at mu), batched reads
    {
        float PV[5] = { mu - 2.5f*sg, mu - 1.9f*sg, mu - 1.45f*sg, mu - 1.1f*sg, mu };
        int CC[5] = {0,0,0,0,0};
        for (int s8 = 0; s8 < 32; s8 += 8){
            float vv[8];
#pragma unroll
            for (int u = 0; u < 8; u++) vv[u] = dw[(s8 + u) * 64 + lane];
#pragma unroll
            for (int pi = 0; pi < 5; pi++){
                int c = 0;
#pragma unroll
                for (int u = 0; u < 8; u++) c += __popcll(__ballot(vv[u] < PV[pi]));
                CC[pi] += c;
            }
        }
#pragma unroll
        for (int pi = 0; pi < 5; pi++){
            if (CC[pi] >= Kn){ if (PV[pi] < hi){ hi = PV[pi]; chi = CC[pi]; } }
            else             { if (PV[pi] > lo){ lo = PV[pi]; clo = CC[pi]; } }
        }
    }

    // refine (usually 0-1 iterations): until chi<=128, batched reads
    for (int it = 0; it < 24 && chi > 128; it++){
        int den = (chi - clo) > 0 ? (chi - clo) : 1;
        float piv = (it & 1) ? 0.5f * (lo + hi)
                             : lo + (hi - lo) * ((float)(96 - clo) / (float)den);
        if (!(piv > lo && piv < hi)) piv = 0.5f * (lo + hi);
        if (!(piv > lo && piv < hi)) break;   // ulp-collapsed: fallback handles
        int c = 0;
        for (int s8 = 0; s8 < 32; s8 += 8){
            float vv[8];
#pragma unroll
            for (int u = 0; u < 8; u++) vv[u] = dw[(s8 + u) * 64 + lane];
#pragma unroll
            for (int u = 0; u < 8; u++) c += __popcll(__ballot(vv[u] < piv));
        }
        if (c >= Kn){ hi = piv; chi = c; } else { lo = piv; clo = c; }
    }

    size_t obase = ((size_t)(b * Nn) + i0 + w) * Kn;

    if (chi <= 128){
        // compact all candidates (< hi) into keybuf via ballot offsets
        keybuf[w][lane]      = ~0ull;
        keybuf[w][lane + 64] = ~0ull;
        unsigned long long me_lower = (1ull << lane) - 1ull;
        int boff = 0;
        for (int s8 = 0; s8 < 32; s8 += 8){
            float vv[8];
#pragma unroll
            for (int u = 0; u < 8; u++) vv[u] = dw[(s8 + u) * 64 + lane];
#pragma unroll
            for (int u = 0; u < 8; u++){
                bool cnd = vv[u] < hi;
                unsigned long long m = __ballot(cnd);
                if (cnd){
                    int o = boff + __popcll(m & me_lower);
                    keybuf[w][o] = (((unsigned long long)enc_f(vv[u])) << 16) | (unsigned)((s8 + u) * 64 + lane);
                }
                boff += __popcll(m);
            }
        }
        // rank my two keys against all chi keys (broadcast LDS reads, unroll 8)
        unsigned long long k0 = keybuf[w][lane];
        unsigned long long k1 = keybuf[w][lane + 64];
        int r0 = 0, r1 = 0;
        int nR = (chi + 7) & ~7;          // <= 128; padding keys are ~0ull
        for (int j2 = 0; j2 < nR; j2 += 8){
            unsigned long long a0 = keybuf[w][j2+0], a1 = keybuf[w][j2+1];
            unsigned long long a2 = keybuf[w][j2+2], a3 = keybuf[w][j2+3];
            unsigned long long a4 = keybuf[w][j2+4], a5 = keybuf[w][j2+5];
            unsigned long long a6 = keybuf[w][j2+6], a7 = keybuf[w][j2+7];
            r0 += (a0<k0)+(a1<k0)+(a2<k0)+(a3<k0)+(a4<k0)+(a5<k0)+(a6<k0)+(a7<k0);
            r1 += (a0<k1)+(a1<k1)+(a2<k1)+(a3<k1)+(a4<k1)+(a5<k1)+(a6<k1)+(a7<k1);
        }
        if (lane < chi      && r0 < Kn) idxout[obase + r0] = (int)(k0 & 0xffffu);
        if (lane + 64 < chi && r1 < Kn) idxout[obase + r1] = (int)(k1 & 0xffffu);
    } else {
        // exact fallback (pathological ties only): iterative wave-min extraction
        unsigned selmask = 0u;
        for (int e = 0; e < Kn; e++){
            unsigned long long best = ~0ull;
#pragma unroll
            for (int s = 0; s < 32; s++){
                float v = dw[s * 64 + lane];
                if (v < hi && !((selmask >> s) & 1)){
                    unsigned long long key = (((unsigned long long)enc_f(v)) << 16) | (unsigned)(s * 64 + lane);
                    best = (key < best) ? key : best;
                }
            }
#pragma unroll
            for (int d = 1; d < 64; d <<= 1){
                unsigned long long ov = __shfl_xor(best, d);
                best = (ov < best) ? ov : best;
            }
            int jj = (int)(best & 0xffffu);
            if ((jj & 63) == lane) selmask |= 1u << (jj >> 6);
            if (lane == 0) idxout[obase + e] = jj;
        }
    }
}

// ---- pre1: p = x@(W1a-W1b)+b1, q = x@W1b  (layer-1 factorization) ----
__global__ __launch_bounds__(256) void pre1_kernel(const float* __restrict__ x,
        const float* __restrict__ w1, const float* __restrict__ b1,
        float* __restrict__ p, float* __restrict__ q){
    int t = threadIdx.x, w = t >> 6, c = t & 63;
    float wd[8], wb[8];
#pragma unroll
    for (int f = 0; f < 8; f++){
        float wbv = w1[(8 + f) * 64 + c];
        wb[f] = wbv;
        wd[f] = w1[f * 64 + c] - wbv;
    }
    float b1c = b1[c];
    int slot = blockIdx.x * 4 + w;                 // 2048 slots
    for (int it = 0; it < 16; it++){
        int node = slot + it * 2048;
        const float* xp = x + (size_t)node * Fin;
        float pv = b1c, qv = 0.f;
#pragma unroll
        for (int f = 0; f < 8; f++){
            float xv = xp[f];
            pv += xv * wd[f]; qv += xv * wb[f];
        }
        p[(size_t)node * 64 + c] = pv;
        q[(size_t)node * 64 + c] = qv;
    }
}

// ---- stats pass 1: moments of z1 = p[i]+q[j] over edges ----
__global__ __launch_bounds__(256) void stats1_kernel(const float* __restrict__ p, const float* __restrict__ q,
        const int* __restrict__ idx, float* __restrict__ sumP, float* __restrict__ ssqP){
    __shared__ float red[2][4][64];
    int t = threadIdx.x, w = t >> 6, c = t & 63;
    float s = 0.f, ss = 0.f;
    int slot = blockIdx.x * 4 + w;                 // 4096 slots
    for (int it = 0; it < 8; it++){
        int node = slot + it * 4096;
        int b = node >> 11;
        float pc = p[(size_t)node * 64 + c];
        const int* ip = idx + (size_t)node * Kn;
        for (int k = 0; k < Kn; k++){
            int j = ip[k];
            float z = pc + q[((size_t)(b << 11) + j) * 64 + c];
            s += z; ss += z * z;
        }
    }
    red[0][w][c] = s; red[1][w][c] = ss;
    __syncthreads();
    if (w == 0){
        sumP[blockIdx.x * 64 + c] = red[0][0][c] + red[0][1][c] + red[0][2][c] + red[0][3][c];
        ssqP[blockIdx.x * 64 + c] = red[1][0][c] + red[1][1][c] + red[1][2][c] + red[1][3][c];
    }
}

// ---- finalize BN params from partials ----
__global__ void finalize_kernel(const float* __restrict__ sumP, const float* __restrict__ ssqP,
        const float* __restrict__ gg, const float* __restrict__ bt,
        float* __restrict__ scale, float* __restrict__ shift, float inv_count){
    int c = threadIdx.x;   // 64 threads
    float s = 0.f, q = 0.f;
    for (int i = 0; i < NSTATB; i++){ s += sumP[i * 64 + c]; q += ssqP[i * 64 + c]; }
    float mu  = s * inv_count;
    float var = q * inv_count - mu * mu;
    float sc  = gg[c] / sqrtf(var + EPSV);
    scale[c] = sc;
    shift[c] = bt[c] - mu * sc;
}

// ---- stats pass 2: z1 -> bn1+relu -> z2 (64x64 matvec, weights in regs), moments ----
__global__ __launch_bounds__(256) void stats2_kernel(const float* __restrict__ p, const float* __restrict__ q,
        const int* __restrict__ idx,
        const float* __restrict__ sc1v, const float* __restrict__ sh1v,
        const float* __restrict__ w2, const float* __restrict__ b2,
        float* __restrict__ sumP, float* __restrict__ ssqP){
    __shared__ float hsh[4][2][64];
    __shared__ float red[2][4][64];
    int t = threadIdx.x, w = t >> 6, c = t & 63;
    float w2c[64];
#pragma unroll
    for (int f = 0; f < 64; f++) w2c[f] = w2[f * 64 + c];
    float sc1 = sc1v[c], sh1 = sh1v[c], b2c = b2[c];
    float s = 0.f, ss = 0.f;
    int slot = blockIdx.x * 4 + w;
    for (int it = 0; it < 8; it++){
        int node = slot + it * 4096;
        int b = node >> 11;
        float pc = p[(size_t)node * 64 + c];
        const int* ip = idx + (size_t)node * Kn;
        for (int k = 0; k < Kn; k++){
            int j = ip[k];
            float z = pc + q[((size_t)(b << 11) + j) * 64 + c];
            float h1 = fmaxf(0.f, z * sc1 + sh1);
            hsh[w][k & 1][c] = h1;
            const float4* h4 = (const float4*)hsh[w][k & 1];
            float z2 = b2c;
#pragma unroll
            for (int f4 = 0; f4 < 16; f4++){
                float4 hv = h4[f4];
                z2 += hv.x * w2c[4*f4] + hv.y * w2c[4*f4+1] + hv.z * w2c[4*f4+2] + hv.w * w2c[4*f4+3];
            }
            s += z2; ss += z2 * z2;
        }
    }
    red[0][w][c] = s; red[1][w][c] = ss;
    __syncthreads();
    if (w == 0){
        sumP[blockIdx.x * 64 + c] = red[0][0][c] + red[0][1][c] + red[0][2][c] + red[0][3][c];
        ssqP[blockIdx.x * 64 + c] = red[1][0][c] + red[1][1][c] + red[1][2][c] + red[1][3][c];
    }
}

// ---- conv1: wave-per-node, layers 2/3 as register-weight matvecs, max over k ----
__global__ __launch_bounds__(256) void conv1_kernel(const float* __restrict__ p, const float* __restrict__ q,
        const int* __restrict__ idx,
        const float* __restrict__ sc1v, const float* __restrict__ sh1v,
        const float* __restrict__ w2, const float* __restrict__ b2,
        const float* __restrict__ sc2v, const float* __restrict__ sh2v,
        const float* __restrict__ w3, const float* __restrict__ b3,
        float* __restrict__ x1){
    __shared__ float hA[4][2][64];
    __shared__ float hB[4][2][64];
    int t = threadIdx.x, w = t >> 6, c = t & 63;
    float w2c[64], w3c[64];
#pragma unroll
    for (int f = 0; f < 64; f++){ w2c[f] = w2[f * 64 + c]; w3c[f] = w3[f * 64 + c]; }
    float sc1 = sc1v[c], sh1 = sh1v[c], sc2 = sc2v[c], sh2 = sh2v[c];
    float b2c = b2[c], b3c = b3[c];
    int node = blockIdx.x * 4 + w;
    int b = node >> 11;
    float pc = p[(size_t)node * 64 + c];
    const int* ip = idx + (size_t)node * Kn;
    float acc = -FLT_MAX;
    for (int k = 0; k < Kn; k++){
        int j = ip[k];
        float z = pc + q[((size_t)(b << 11) + j) * 64 + c];
        float h1 = fmaxf(0.f, z * sc1 + sh1);
        hA[w][k & 1][c] = h1;
        const float4* h4 = (const float4*)hA[w][k & 1];
        float z2 = b2c;
#pragma unroll
        for (int f4 = 0; f4 < 16; f4++){
            float4 hv = h4[f4];
            z2 += hv.x * w2c[4*f4] + hv.y * w2c[4*f4+1] + hv.z * w2c[4*f4+2] + hv.w * w2c[4*f4+3];
        }
        float h2 = fmaxf(0.f, z2 * sc2 + sh2);
        hB[w][k & 1][c] = h2;
        const float4* g4 = (const float4*)hB[w][k & 1];
        float z3 = b3c;
#pragma unroll
        for (int f4 = 0; f4 < 16; f4++){
            float4 hv = g4[f4];
            z3 += hv.x * w3c[4*f4] + hv.y * w3c[4*f4+1] + hv.z * w3c[4*f4+2] + hv.w * w3c[4*f4+3];
        }
        acc = fmaxf(acc, z3);
    }
    x1[(size_t)node * 64 + c] = acc;
}

// ---- pre2: u = x1@(W4a-W4b)+b4 (into x2 buffer), v = x1@W4b ----
__global__ __launch_bounds__(256) void pre2_kernel(const float* __restrict__ x1,
        const float* __restrict__ w4, const float* __restrict__ b4,
        float* __restrict__ u, float* __restrict__ v){
    __shared__ float x1s[16][64];
    int t = threadIdx.x;
    int c = t & 127, h = t >> 7;
    float wd[64], wb[64];
#pragma unroll
    for (int f = 0; f < 64; f++){
        float wbv = w4[(64 + f) * 128 + c];
        wb[f] = wbv;
        wd[f] = w4[f * 128 + c] - wbv;
    }
    float b4c = b4[c];
    int base = blockIdx.x * 16;
    for (int i = t; i < 16 * 64; i += 256)
        x1s[i >> 6][i & 63] = x1[(size_t)(base + (i >> 6)) * 64 + (i & 63)];
    __syncthreads();
    for (int n = 0; n < 8; n++){
        int node = base + h * 8 + n;
        const float4* xr = (const float4*)x1s[h * 8 + n];
        float uv = b4c, vv = 0.f;
#pragma unroll
        for (int f4 = 0; f4 < 16; f4++){
            float4 xv = xr[f4];
            uv += xv.x * wd[4*f4] + xv.y * wd[4*f4+1] + xv.z * wd[4*f4+2] + xv.w * wd[4*f4+3];
            vv += xv.x * wb[4*f4] + xv.y * wb[4*f4+1] + xv.z * wb[4*f4+2] + xv.w * wb[4*f4+3];
        }
        u[(size_t)node * 128 + c] = uv;
        v[(size_t)node * 128 + c] = vv;
    }
}

// ---- gmax2: x2[i][c] = u[i][c] + max_k v[j_k][c]  (x2 holds u on entry) ----
__global__ __launch_bounds__(256) void gmax2_kernel(const float* __restrict__ v, const int* __restrict__ idx,
        float* __restrict__ x2){
    int t = threadIdx.x, g = t >> 7, c = t & 127;
    int node = blockIdx.x * 2 + g;
    int b = node >> 11;
    const int* ip = idx + (size_t)node * Kn;
    float vm = -FLT_MAX;
    for (int k = 0; k < Kn; k++){
        int j = ip[k];
        vm = fmaxf(vm, v[((size_t)(b << 11) + j) * 128 + c]);
    }
    x2[(size_t)node * 128 + c] += vm;
}

// ---- out = cat(x1,x2) @ w5 + b5, global max over nodes (encoded atomics) ----
__global__ __launch_bounds__(256) void outpool_kernel(const float* __restrict__ x1, const float* __restrict__ x2,
        const float* __restrict__ w5, const float* __restrict__ b5, unsigned* __restrict__ pooled){
    __shared__ float rows[8][192];
    int t = threadIdx.x;
    int node0 = blockIdx.x * 8;
    for (int i = t; i < 8 * 192; i += 256){
        int e = i / 192, f = i - e * 192;
        int nd = node0 + e;
        rows[e][f] = (f < 64) ? x1[(size_t)nd * 64 + f] : x2[(size_t)nd * 128 + f - 64];
    }
    __syncthreads();
    float z[8];
#pragma unroll
    for (int e = 0; e < 8; e++) z[e] = b5[t];
    for (int f = 0; f < 192; f++){
        float w = w5[f * 256 + t];
#pragma unroll
        for (int e = 0; e < 8; e++) z[e] += rows[e][f] * w;
    }
    float m = z[0];
#pragma unroll
    for (int e = 1; e < 8; e++) m = fmaxf(m, z[e]);
    int b = node0 >> 11;
    atomicMax(&pooled[b * 256 + t], enc_f(m));
}

// ---- head: decode pooled, MLP [256,128,64,4] with training-mode BN over 16 ----
__global__ __launch_bounds__(256) void head_kernel(const unsigned* __restrict__ pooledE,
        const float* __restrict__ w6, const float* __restrict__ b6, const float* __restrict__ g6, const float* __restrict__ bt6,
        const float* __restrict__ w7, const float* __restrict__ b7, const float* __restrict__ g7, const float* __restrict__ bt7,
        const float* __restrict__ w8, const float* __restrict__ b8, float* __restrict__ out){
    __shared__ float P[16][256];
    __shared__ float H6[16][128];
    __shared__ float H7[16][64];
    int t = threadIdx.x;
    for (int i = t; i < 16 * 256; i += 256) P[i >> 8][i & 255] = dec_f(pooledE[i]);
    __syncthreads();
    for (int i = t; i < 16 * 128; i += 256){
        int r = i >> 7, c = i & 127;
        float z = b6[c];
        for (int f = 0; f < 256; f++) z += P[r][f] * w6[f * 128 + c];
        H6[r][c] = z;
    }
    __syncthreads();
    if (t < 128){
        float s = 0.f, q = 0.f;
        for (int r = 0; r < 16; r++){ float v = H6[r][t]; s += v; q += v * v; }
        float mu = s * (1.f / 16.f);
        float var = q * (1.f / 16.f) - mu * mu;
        float sc = g6[t] / sqrtf(var + EPSV);
        float sh = bt6[t] - mu * sc;
        for (int r = 0; r < 16; r++) H6[r][t] = fmaxf(0.f, H6[r][t] * sc + sh);
    }
    __syncthreads();
    for (int i = t; i < 16 * 64; i += 256){
        int r = i >> 6, c = i & 63;
        float z = b7[c];
        for (int f = 0; f < 128; f++) z += H6[r][f] * w7[f * 64 + c];
        H7[r][c] = z;
    }
    __syncthreads();
    if (t < 64){
        float s = 0.f, q = 0.f;
        for (int r = 0; r < 16; r++){ float v = H7[r][t]; s += v; q += v * v; }
        float mu = s * (1.f / 16.f);
        float var = q * (1.f / 16.f) - mu * mu;
        float sc = g7[t] / sqrtf(var + EPSV);
        float sh = bt7[t] - mu * sc;
        for (int r = 0; r < 16; r++) H7[r][t] = fmaxf(0.f, H7[r][t] * sc + sh);
    }
    __syncthreads();
    if (t < 64){
        int r = t >> 2, c = t & 3;
        float z = b8[c];
        for (int f = 0; f < 64; f++) z += H7[r][f] * w8[f * 4 + c];
        out[t] = z;
    }
}

extern "C" void kernel_launch(void* const* d_in, const int* in_sizes, int n_in,
                              void* d_out, int out_size, void* d_ws, size_t ws_size,
                              hipStream_t stream){
    const float* x   = (const float*)d_in[0];
    const float* w1  = (const float*)d_in[1];
    const float* b1  = (const float*)d_in[2];
    const float* g1  = (const float*)d_in[3];
    const float* bt1 = (const float*)d_in[4];
    const float* w2  = (const float*)d_in[5];
    const float* b2  = (const float*)d_in[6];
    const float* g2  = (const float*)d_in[7];
    const float* bt2 = (const float*)d_in[8];
    const float* w3  = (const float*)d_in[9];
    const float* b3  = (const float*)d_in[10];
    const float* w4  = (const float*)d_in[11];
    const float* b4  = (const float*)d_in[12];
    const float* w5  = (const float*)d_in[13];
    const float* b5  = (const float*)d_in[14];
    const float* w6  = (const float*)d_in[15];
    const float* b6  = (const float*)d_in[16];
    const float* g6  = (const float*)d_in[17];
    const float* bt6 = (const float*)d_in[18];
    const float* w7  = (const float*)d_in[19];
    const float* b7  = (const float*)d_in[20];
    const float* g7  = (const float*)d_in[21];
    const float* bt7 = (const float*)d_in[22];
    const float* w8  = (const float*)d_in[23];
    const float* b8  = (const float*)d_in[24];
    float* out = (float*)d_out;

    char* ws = (char*)d_ws;
    size_t off = 0;
    auto alloc = [&](size_t bytes)->char*{
        char* p = ws + off;
        off += (bytes + 255) & ~(size_t)255;
        return p;
    };
    int*      idx1   = (int*)alloc((size_t)EDG * 4);
    int*      idx2   = (int*)alloc((size_t)EDG * 4);
    float*    sq1    = (float*)alloc((size_t)NODES * 4);
    float*    sq2    = (float*)alloc((size_t)NODES * 4);
    float*    x1     = (float*)alloc((size_t)NODES * 64 * 4);
    float*    x2     = (float*)alloc((size_t)NODES * 128 * 4);
    float*    sumP   = (float*)alloc((size_t)NSTATB * 64 * 4);
    float*    ssqP   = (float*)alloc((size_t)NSTATB * 64 * 4);
    float*    scale1 = (float*)alloc(64 * 4);
    float*    shift1 = (float*)alloc(64 * 4);
    float*    scale2 = (float*)alloc(64 * 4);
    float*    shift2 = (float*)alloc(64 * 4);
    unsigned* pooled = (unsigned*)alloc((size_t)Bn * 256 * 4);
    float*    p      = (float*)alloc((size_t)NODES * 64 * 4);
    float*    q      = (float*)alloc((size_t)NODES * 64 * 4);
    float*    v      = p;   // overlay: p,q are dead once conv1 finishes; v = 128 floats/node spans p+q

    hipMemsetAsync(pooled, 0, (size_t)Bn * 256 * 4, stream);

    sq_kernel<8><<<(NODES + 255) / 256, 256, 0, stream>>>(x, sq1);
    knn_kernel<8><<<NODES / 4, 256, 0, stream>>>(x, sq1, idx1);
    pre1_kernel<<<512, 256, 0, stream>>>(x, w1, b1, p, q);
    stats1_kernel<<<NSTATB, 256, 0, stream>>>(p, q, idx1, sumP, ssqP);
    finalize_kernel<<<1, 64, 0, stream>>>(sumP, ssqP, g1, bt1, scale1, shift1, 1.0f / (float)EDG);
    stats2_kernel<<<NSTATB, 256, 0, stream>>>(p, q, idx1, scale1, shift1, w2, b2, sumP, ssqP);
    finalize_kernel<<<1, 64, 0, stream>>>(sumP, ssqP, g2, bt2, scale2, shift2, 1.0f / (float)EDG);
    conv1_kernel<<<NODES / 4, 256, 0, stream>>>(p, q, idx1, scale1, shift1,
                                                w2, b2, scale2, shift2, w3, b3, x1);
    sq_kernel<64><<<(NODES + 255) / 256, 256, 0, stream>>>(x1, sq2);
    knn_kernel<64><<<NODES / 4, 256, 0, stream>>>(x1, sq2, idx2);
    pre2_kernel<<<NODES / 16, 256, 0, stream>>>(x1, w4, b4, x2, v);
    gmax2_kernel<<<NODES / 2, 256, 0, stream>>>(v, idx2, x2);
    outpool_kernel<<<NODES / 8, 256, 0, stream>>>(x1, x2, w5, b5, pooled);
    head_kernel<<<1, 256, 0, stream>>>(pooled, w6, b6, g6, bt6, w7, b7, g7, bt7, w8, b8, out);
}